// Round 4
// baseline (469.057 us; speedup 1.0000x reference)
//
#include <hip/hip_runtime.h>
#include <hip/hip_bf16.h>
#include <hip/hip_cooperative_groups.h>
#include <math.h>

namespace cg = cooperative_groups;

// Problem constants
#define NB 2
#define CC 256
#define NPOS 2304   // 48*48
#define NDELTA 95

typedef __attribute__((ext_vector_type(8))) short short8;
typedef __attribute__((ext_vector_type(4))) float floatx4;

__device__ inline unsigned short f2bf(float x) {
    unsigned int u = __float_as_uint(x);
    u = (u + 0x7FFFu + ((u >> 16) & 1u)) >> 16;
    return (unsigned short)u;
}
__device__ inline float bf2f(unsigned short h) {
    return __uint_as_float(((unsigned int)h) << 16);
}
__device__ inline unsigned int pk2(float a, float b) {
    return (unsigned int)f2bf(a) | ((unsigned int)f2bf(b) << 16);
}
__device__ inline unsigned int pkmul(unsigned int a, unsigned int b) {
    __hip_bfloat162 x = *(__hip_bfloat162*)&a;
    __hip_bfloat162 y = *(__hip_bfloat162*)&b;
    __hip_bfloat162 r = __hmul2(x, y);
    return *(unsigned int*)&r;
}

// ===========================================================================
// Stage bodies — IDENTICAL code used by both the 6-kernel fallback path and
// the cooperative mega-kernel. All verbatim from the verified 152.9us build.
// ===========================================================================

// ---- Stage A: prep + extract (1064 tasks) ---------------------------------
__device__ __forceinline__ void stageA_body(int task, int t,
    const float* __restrict__ Wx, const float* __restrict__ Wy,
    const float* __restrict__ Wk, const float* __restrict__ ab,
    const float* __restrict__ Wq, const float* __restrict__ Wv,
    const float* __restrict__ Wp, const float* __restrict__ x,
    unsigned short* __restrict__ posxb, unsigned short* __restrict__ posyb,
    unsigned short* __restrict__ Wb, unsigned short* __restrict__ Wpb,
    unsigned short* __restrict__ xs_t)
{
    __shared__ __align__(16) unsigned short Lt[64][264];
    if (task < NDELTA) {
        float* emb = (float*)&Lt[0][0];
        float delta = (float)(task - 47);
        if (t < 64) {
            float dim_inv = exp2f(-(float)t * 0.15571537944784511f); // log2(1000)/64
            float ang = 2.0f * delta * dim_inv;
            emb[t]      = sinf(ang);
            emb[t + 64] = cosf(ang);
        }
        __syncthreads();
        float sx = 0.f, sy = 0.f;
        const float* wxr = Wx + t * 128;
        const float* wyr = Wy + t * 128;
        for (int f = 0; f < 128; ++f) {
            float e = emb[f];
            sx += e * wxr[f];
            sy += e * wyr[f];
        }
        const float inv_sqrt2 = 0.70710678118654752440f;
        int g = t >> 5, d = t & 31;
        posxb[((size_t)g * 96 + task) * 32 + d] = f2bf(sx * inv_sqrt2);
        posyb[((size_t)g * 96 + task) * 32 + d] = f2bf(sy * inv_sqrt2);
    } else if (task == NDELTA) {
        int g = t >> 5, d = t & 31;
        posxb[((size_t)g * 96 + 95) * 32 + d] = 0;
        posyb[((size_t)g * 96 + 95) * 32 + d] = 0;
    } else if (task < 96 + 640) {
        int o = task - 96;
        float v = 0.f;
        if (o < 256)      v = Wq[o * 256 + t];
        else if (o < 512) v = Wv[(o - 256) * 256 + t];
        else if (o < 520) {
            int g = o - 512;
            float s = 0.f;
            for (int d = 0; d < 32; ++d)
                s += ab[g * 32 + d] * Wk[(g * 32 + d) * 256 + t];
            v = s;
        }
        Wb[(size_t)o * 256 + t] = f2bf(v);
    } else if (task < 992) {
        int o = task - 736;
        Wpb[(size_t)o * 256 + t] = f2bf(Wp[o * 256 + t]);
    } else {
        // extract x[:, :, ::2, ::2] -> bf16 transposed
        int blk = task - 992;
        int pt = blk % 36;
        int n = blk / 36;
        int p0 = pt * 64;
        int cw = t >> 4;      // 0..15
        int pl = t & 15;
        for (int cc = 0; cc < 16; ++cc) {
            int c = cc * 16 + cw;
            const float* src = x + ((size_t)(n * 256 + c)) * (96 * 96);
            #pragma unroll
            for (int k = 0; k < 4; ++k) {
                int p = p0 + pl + k * 16;
                int i = p / 48, j = p - i * 48;
                Lt[pl + k * 16][c] = f2bf(src[(2 * i) * 96 + 2 * j]);
            }
        }
        __syncthreads();
        #pragma unroll
        for (int it = 0; it < 8; ++it) {
            int s = t + it * 256;
            int p = s >> 5, c8 = s & 31;
            uint4 v = *(const uint4*)&Lt[p][c8 * 8];
            *(uint4*)(xs_t + ((size_t)(n * NPOS + p0 + p)) * 256 + c8 * 8) = v;
        }
    }
}

// ---- Stage B: qkv projection (360 tasks) ----------------------------------
__device__ __forceinline__ void stageB_body(int task, int t,
    const unsigned short* __restrict__ xs_t, const unsigned short* __restrict__ Wb,
    unsigned short* __restrict__ qbuf, float* __restrict__ vbuf,
    float* __restrict__ ek)
{
    int mT = task % 5;
    int nT = task / 5;
    int wm = t >> 6, L = t & 63, l16 = L & 15, oct = L >> 4;
    int colBase = nT * 64;
    int n = colBase / NPOS;
    int p0 = colBase - n * NPOS;
    int o_w = mT * 128 + wm * 32;

    const unsigned short* A0 = Wb + (size_t)(o_w + l16) * 256 + oct * 8;
    const unsigned short* A1 = A0 + 16 * 256;
    const unsigned short* B0 = xs_t + ((size_t)(n * NPOS + p0 + l16)) * 256 + oct * 8;

    floatx4 acc[2][4] = {};
    #pragma unroll
    for (int kc = 0; kc < 8; ++kc) {
        int k0 = kc * 32;
        short8 a0 = *(const short8*)(A0 + k0);
        short8 a1 = *(const short8*)(A1 + k0);
        short8 b0 = *(const short8*)(B0 + k0);
        short8 b1 = *(const short8*)(B0 + 16 * 256 + k0);
        short8 b2 = *(const short8*)(B0 + 32 * 256 + k0);
        short8 b3 = *(const short8*)(B0 + 48 * 256 + k0);
        acc[0][0] = __builtin_amdgcn_mfma_f32_16x16x32_bf16(a0, b0, acc[0][0], 0, 0, 0);
        acc[0][1] = __builtin_amdgcn_mfma_f32_16x16x32_bf16(a0, b1, acc[0][1], 0, 0, 0);
        acc[0][2] = __builtin_amdgcn_mfma_f32_16x16x32_bf16(a0, b2, acc[0][2], 0, 0, 0);
        acc[0][3] = __builtin_amdgcn_mfma_f32_16x16x32_bf16(a0, b3, acc[0][3], 0, 0, 0);
        acc[1][0] = __builtin_amdgcn_mfma_f32_16x16x32_bf16(a1, b0, acc[1][0], 0, 0, 0);
        acc[1][1] = __builtin_amdgcn_mfma_f32_16x16x32_bf16(a1, b1, acc[1][1], 0, 0, 0);
        acc[1][2] = __builtin_amdgcn_mfma_f32_16x16x32_bf16(a1, b2, acc[1][2], 0, 0, 0);
        acc[1][3] = __builtin_amdgcn_mfma_f32_16x16x32_bf16(a1, b3, acc[1][3], 0, 0, 0);
    }

    if (o_w < 256) {
        #pragma unroll
        for (int af = 0; af < 2; ++af) {
            int ob = o_w + af * 16 + oct * 4;
            int g = ob >> 5, d0 = ob & 31;
            #pragma unroll
            for (int f = 0; f < 4; ++f) {
                int p = p0 + f * 16 + l16;
                uint2 w;
                w.x = pk2(acc[af][f][0], acc[af][f][1]);
                w.y = pk2(acc[af][f][2], acc[af][f][3]);
                *(uint2*)&qbuf[((size_t)(n * 8 + g) * NPOS + p) * 32 + d0] = w;
            }
        }
    } else if (o_w < 512) {
        #pragma unroll
        for (int af = 0; af < 2; ++af) {
            #pragma unroll
            for (int f = 0; f < 4; ++f) {
                int p = p0 + f * 16 + l16;
                #pragma unroll
                for (int r = 0; r < 4; ++r) {
                    int o = o_w + af * 16 + oct * 4 + r;
                    vbuf[((size_t)(n * 256 + (o - 256))) * NPOS + p] = acc[af][f][r];
                }
            }
        }
    } else {
        #pragma unroll
        for (int af = 0; af < 2; ++af) {
            #pragma unroll
            for (int f = 0; f < 4; ++f) {
                int p = p0 + f * 16 + l16;
                #pragma unroll
                for (int r = 0; r < 4; ++r) {
                    int o = o_w + af * 16 + oct * 4 + r;
                    if (o < 520)
                        ek[((size_t)(n * 8 + (o - 512))) * NPOS + p] = acc[af][f][r];
                }
            }
        }
    }
}

// ---- Stage C: vhat (384 tasks) --------------------------------------------
__device__ __forceinline__ void stageC_body(int task, int t,
    const float* __restrict__ vbuf, const float* __restrict__ ek,
    uint4* __restrict__ vhat)
{
    int tile = task % 24;
    int ng = task / 24;
    int k0 = tile * 96;
    const float* vb = vbuf + (size_t)ng * 32 * NPOS;
    uint4* outv = vhat + ((size_t)ng * 24 + tile) * 576;

    __shared__ __align__(16) float Ae[96];
    if (t < 96) Ae[t] = __expf(ek[(size_t)ng * NPOS + k0 + t]);
    __syncthreads();

    for (int s = t; s < 576; s += 256) {
        int grp = s >> 6;
        int Ls = s & 63;
        int cc = grp / 3;
        int nn = grp - cc * 3;
        int koct = cc * 32 + ((Ls >> 4) << 3);
        uint4 w = make_uint4(0u, 0u, 0u, 0u);
        if (nn < 2) {
            int d = nn * 16 + (Ls & 15);
            const float* vp = vb + (size_t)d * NPOS + k0 + koct;
            const float* ap = Ae + koct;
            float4 v0 = *(const float4*)vp;
            float4 v1 = *(const float4*)(vp + 4);
            float4 a0 = *(const float4*)ap;
            float4 a1 = *(const float4*)(ap + 4);
            w.x = pk2(v0.x * a0.x, v0.y * a0.y);
            w.y = pk2(v0.z * a0.z, v0.w * a0.w);
            w.z = pk2(v1.x * a1.x, v1.y * a1.y);
            w.w = pk2(v1.z * a1.z, v1.w * a1.w);
        } else if ((Ls & 15) == 0) {
            const float* ap = Ae + koct;
            float4 a0 = *(const float4*)ap;
            float4 a1 = *(const float4*)(ap + 4);
            w.x = pk2(a0.x, a0.y);
            w.y = pk2(a0.z, a0.w);
            w.z = pk2(a1.x, a1.y);
            w.w = pk2(a1.z, a1.w);
        }
        outv[s] = w;
    }
}

// ---- Stage D: attention (576 tasks, verified r8 block structure) ----------
#define DO_TILE(BB, TT) do {                                                   \
    int u0_ = (TT) * 2;                                                        \
    unsigned int y0_ = Ys[qp * 50 + u0_];     y0_ |= y0_ << 16;                \
    unsigned int y1_ = Ys[qp * 50 + u0_ + 1]; y1_ |= y1_ << 16;                \
    unsigned int Yc0_ = y0_, Yc1_ = (o < 2) ? y0_ : y1_, Yc2_ = y1_;           \
    union { unsigned int u[4]; short8 s; } av_;                                \
    av_.u[0] = pkmul(Xp[0], Yc0_); av_.u[1] = pkmul(Xp[1], Yc0_);              \
    av_.u[2] = pkmul(Xp[2], Yc0_); av_.u[3] = pkmul(Xp[3], Yc0_);              \
    acc0 = __builtin_amdgcn_mfma_f32_16x16x32_bf16(av_.s, *(const short8*)&BB[0], acc0, 0, 0, 0); \
    acc1 = __builtin_amdgcn_mfma_f32_16x16x32_bf16(av_.s, *(const short8*)&BB[1], acc1, 0, 0, 0); \
    acc2 = __builtin_amdgcn_mfma_f32_16x16x32_bf16(av_.s, *(const short8*)&BB[2], acc2, 0, 0, 0); \
    av_.u[0] = pkmul(Xp[4], Yc1_); av_.u[1] = pkmul(Xp[5], Yc1_);              \
    av_.u[2] = pkmul(Xp[6], Yc1_); av_.u[3] = pkmul(Xp[7], Yc1_);              \
    acc0 = __builtin_amdgcn_mfma_f32_16x16x32_bf16(av_.s, *(const short8*)&BB[3], acc0, 0, 0, 0); \
    acc1 = __builtin_amdgcn_mfma_f32_16x16x32_bf16(av_.s, *(const short8*)&BB[4], acc1, 0, 0, 0); \
    acc2 = __builtin_amdgcn_mfma_f32_16x16x32_bf16(av_.s, *(const short8*)&BB[5], acc2, 0, 0, 0); \
    av_.u[0] = pkmul(Xp[8], Yc2_); av_.u[1] = pkmul(Xp[9], Yc2_);              \
    av_.u[2] = pkmul(Xp[10], Yc2_); av_.u[3] = pkmul(Xp[11], Yc2_);            \
    acc0 = __builtin_amdgcn_mfma_f32_16x16x32_bf16(av_.s, *(const short8*)&BB[6], acc0, 0, 0, 0); \
    acc1 = __builtin_amdgcn_mfma_f32_16x16x32_bf16(av_.s, *(const short8*)&BB[7], acc1, 0, 0, 0); \
    acc2 = __builtin_amdgcn_mfma_f32_16x16x32_bf16(av_.s, *(const short8*)&BB[8], acc2, 0, 0, 0); \
} while (0)

__device__ __forceinline__ void stageD_body(int task, int t,
    const unsigned short* __restrict__ qbuf, const unsigned short* __restrict__ posxb,
    const unsigned short* __restrict__ posyb, const uint4* __restrict__ vhat,
    unsigned short* __restrict__ oattn_t)
{
    __shared__ unsigned short Xs[64 * 50];
    __shared__ unsigned short Ys[64 * 50];
    __shared__ float linv_s[64];

    int qt = task % 36;
    int ng = task / 36;
    int nb = ng >> 3, g = ng & 7;
    int qbase = qt * 64;
    int m = t >> 6, L = t & 63;
    int l16 = L & 15, oct = L >> 4;

    // ---- prologue: T = Q·pos^T via MFMA, X/Y = exp(T) into LDS ----
    {
        int qtile0 = qbase + m * 16;
        int hq = qtile0 / 48;
        int wq0 = qtile0 - hq * 48;
        short8 aq = *(const short8*)(qbuf +
            ((size_t)ng * NPOS + qtile0 + l16) * 32 + oct * 8);
        const unsigned short* pxg = posxb + (size_t)g * 96 * 32;
        const unsigned short* pyg = posyb + (size_t)g * 96 * 32;
        floatx4 zero = {0.f, 0.f, 0.f, 0.f};
        #pragma unroll
        for (int j = 0; j < 6; ++j) {
            int dl = j * 16 + l16;
            short8 bx = *(const short8*)(pxg + (size_t)dl * 32 + oct * 8);
            short8 by = *(const short8*)(pyg + (size_t)dl * 32 + oct * 8);
            floatx4 tx = __builtin_amdgcn_mfma_f32_16x16x32_bf16(aq, bx, zero, 0, 0, 0);
            floatx4 ty = __builtin_amdgcn_mfma_f32_16x16x32_bf16(aq, by, zero, 0, 0, 0);
            int u = hq + 47 - dl;
            bool uok = (u >= 0) && (u < 48);
            #pragma unroll
            for (int r = 0; r < 4; ++r) {
                int ql = oct * 4 + r;
                int v = wq0 + ql + 47 - dl;
                if (v >= 0 && v < 48)
                    Xs[(m * 16 + ql) * 50 + v] = f2bf(__expf(tx[r]));
                if (uok)
                    Ys[(m * 16 + ql) * 50 + u] = f2bf(__expf(ty[r]));
            }
        }
    }
    __syncthreads();

    int qp = m * 16 + l16;
    int o = oct;
    unsigned int Xp[12];
    #pragma unroll
    for (int c = 0; c < 3; ++c)
        #pragma unroll
        for (int jj = 0; jj < 4; ++jj) {
            int k = c * 32 + o * 8 + jj * 2;
            int v0 = (k < 48) ? k : k - 48;
            Xp[c * 4 + jj] = *(const unsigned int*)&Xs[qp * 50 + v0];
        }

    floatx4 acc0 = {0.f, 0.f, 0.f, 0.f};
    floatx4 acc1 = {0.f, 0.f, 0.f, 0.f};
    floatx4 acc2 = {0.f, 0.f, 0.f, 0.f};

    const uint4* vb = vhat + (size_t)ng * 24 * 576 + L;
    uint4 Abuf[9], Bbuf[9];
    #pragma unroll
    for (int gg = 0; gg < 9; ++gg) Abuf[gg] = vb[gg * 64];

    for (int tile = 0; tile < 24; tile += 2) {
        const uint4* sB = vb + (tile + 1) * 576;
        #pragma unroll
        for (int gg = 0; gg < 9; ++gg) Bbuf[gg] = sB[gg * 64];
        DO_TILE(Abuf, tile);
        if (tile + 2 < 24) {
            const uint4* sA = vb + (tile + 2) * 576;
            #pragma unroll
            for (int gg = 0; gg < 9; ++gg) Abuf[gg] = sA[gg * 64];
        }
        DO_TILE(Bbuf, tile + 1);
    }

    if ((L & 15) == 0) {
        int qc = m * 16 + (L >> 4) * 4;
        #pragma unroll
        for (int r = 0; r < 4; ++r)
            linv_s[qc + r] = 1.0f / acc2[r];
    }
    __syncthreads();
    {
        int qc = m * 16 + (L >> 4) * 4;
        int d0 = L & 15;
        #pragma unroll
        for (int r = 0; r < 4; ++r) {
            float lir = linv_s[qc + r];
            size_t row = ((size_t)nb * NPOS + qbase + qc + r) * 256;
            oattn_t[row + g * 32 + d0]      = f2bf(acc0[r] * lir);
            oattn_t[row + g * 32 + 16 + d0] = f2bf(acc1[r] * lir);
        }
    }
}

// ---- Stage E: output projection (144 tasks) -------------------------------
__device__ __forceinline__ void stageE_body(int task, int t,
    const unsigned short* __restrict__ oattn_t, const unsigned short* __restrict__ Wpb,
    const float* __restrict__ bpv, unsigned short* __restrict__ projb)
{
    int mT = task & 1;
    int nT = task >> 1;
    int wm = t >> 6, L = t & 63, l16 = L & 15, oct = L >> 4;
    int colBase = nT * 64;
    int n = colBase / NPOS;
    int p0 = colBase - n * NPOS;
    int o_w = mT * 128 + wm * 32;

    const unsigned short* A0 = Wpb + (size_t)(o_w + l16) * 256 + oct * 8;
    const unsigned short* A1 = A0 + 16 * 256;
    const unsigned short* B0 = oattn_t + ((size_t)(n * NPOS + p0 + l16)) * 256 + oct * 8;

    floatx4 acc[2][4] = {};
    #pragma unroll
    for (int kc = 0; kc < 8; ++kc) {
        int k0 = kc * 32;
        short8 a0 = *(const short8*)(A0 + k0);
        short8 a1 = *(const short8*)(A1 + k0);
        short8 b0 = *(const short8*)(B0 + k0);
        short8 b1 = *(const short8*)(B0 + 16 * 256 + k0);
        short8 b2 = *(const short8*)(B0 + 32 * 256 + k0);
        short8 b3 = *(const short8*)(B0 + 48 * 256 + k0);
        acc[0][0] = __builtin_amdgcn_mfma_f32_16x16x32_bf16(a0, b0, acc[0][0], 0, 0, 0);
        acc[0][1] = __builtin_amdgcn_mfma_f32_16x16x32_bf16(a0, b1, acc[0][1], 0, 0, 0);
        acc[0][2] = __builtin_amdgcn_mfma_f32_16x16x32_bf16(a0, b2, acc[0][2], 0, 0, 0);
        acc[0][3] = __builtin_amdgcn_mfma_f32_16x16x32_bf16(a0, b3, acc[0][3], 0, 0, 0);
        acc[1][0] = __builtin_amdgcn_mfma_f32_16x16x32_bf16(a1, b0, acc[1][0], 0, 0, 0);
        acc[1][1] = __builtin_amdgcn_mfma_f32_16x16x32_bf16(a1, b1, acc[1][1], 0, 0, 0);
        acc[1][2] = __builtin_amdgcn_mfma_f32_16x16x32_bf16(a1, b2, acc[1][2], 0, 0, 0);
        acc[1][3] = __builtin_amdgcn_mfma_f32_16x16x32_bf16(a1, b3, acc[1][3], 0, 0, 0);
    }

    #pragma unroll
    for (int af = 0; af < 2; ++af) {
        #pragma unroll
        for (int f = 0; f < 4; ++f) {
            int p = p0 + f * 16 + l16;
            #pragma unroll
            for (int r = 0; r < 4; ++r) {
                int o = o_w + af * 16 + oct * 4 + r;
                projb[((size_t)(n * 256 + o)) * NPOS + p] = f2bf(acc[af][f][r] + bpv[o]);
            }
        }
    }
}

// ---- Stage F: bilinear resize + residual (4608 tasks) ---------------------
__device__ __forceinline__ void stageF_body(int task, int t,
    const unsigned short* __restrict__ projb, const float* __restrict__ x,
    const float* __restrict__ gamma, float* __restrict__ out)
{
    int idx4 = task * 256 + t;
    int J0 = (idx4 % 24) * 4;
    int tmp = idx4 / 24;
    int I = tmp % 96;
    int nc = tmp / 96;

    int jr = I >> 1;
    int r0, r1; float w0, w1;
    if ((I & 1) == 0) { r0 = (jr > 0) ? jr - 1 : 0; r1 = jr; w0 = 0.25f; w1 = 0.75f; }
    else              { r0 = jr; r1 = (jr < 47) ? jr + 1 : 47; w0 = 0.75f; w1 = 0.25f; }

    const unsigned short* P = projb + (size_t)nc * NPOS;
    size_t base = ((size_t)nc * 96 + I) * 96 + J0;
    float4 xv = *(const float4*)(x + base);
    float gm = gamma[0];
    float4 ov;
    #pragma unroll
    for (int k = 0; k < 4; ++k) {
        int J = J0 + k;
        int jc = J >> 1;
        int c0, c1; float u0, u1;
        if ((J & 1) == 0) { c0 = (jc > 0) ? jc - 1 : 0; c1 = jc; u0 = 0.25f; u1 = 0.75f; }
        else              { c0 = jc; c1 = (jc < 47) ? jc + 1 : 47; u0 = 0.75f; u1 = 0.25f; }
        float v = w0 * (u0 * bf2f(P[r0 * 48 + c0]) + u1 * bf2f(P[r0 * 48 + c1])) +
                  w1 * (u0 * bf2f(P[r1 * 48 + c0]) + u1 * bf2f(P[r1 * 48 + c1]));
        float xr = (k == 0) ? xv.x : (k == 1) ? xv.y : (k == 2) ? xv.z : xv.w;
        float oo = gm * v + xr;
        if (k == 0) ov.x = oo; else if (k == 1) ov.y = oo;
        else if (k == 2) ov.z = oo; else ov.w = oo;
    }
    *(float4*)(out + base) = ov;
}

// ===========================================================================
// Fallback standalone kernels (verified 6-launch path)
// ===========================================================================
__global__ __launch_bounds__(256) void prep_extract_kernel(
    const float* Wx, const float* Wy, const float* Wk, const float* ab,
    const float* Wq, const float* Wv, const float* Wp, const float* x,
    unsigned short* posxb, unsigned short* posyb,
    unsigned short* Wb, unsigned short* Wpb, unsigned short* xs_t)
{
    stageA_body(blockIdx.x, threadIdx.x, Wx, Wy, Wk, ab, Wq, Wv, Wp, x,
                posxb, posyb, Wb, Wpb, xs_t);
}

__global__ __launch_bounds__(256, 2) void qkv_kernel(
    const unsigned short* xs_t, const unsigned short* Wb,
    unsigned short* qbuf, float* vbuf, float* ek)
{
    stageB_body(blockIdx.x, threadIdx.x, xs_t, Wb, qbuf, vbuf, ek);
}

__global__ __launch_bounds__(256) void vhat_kernel(
    const float* vbuf, const float* ek, uint4* vhat)
{
    stageC_body(blockIdx.x, threadIdx.x, vbuf, ek, vhat);
}

__global__ __launch_bounds__(256, 2) void attn_kernel(
    const unsigned short* qbuf, const unsigned short* posxb,
    const unsigned short* posyb, const uint4* vhat, unsigned short* oattn_t)
{
    stageD_body(blockIdx.x, threadIdx.x, qbuf, posxb, posyb, vhat, oattn_t);
}

__global__ __launch_bounds__(256, 2) void proj_kernel(
    const unsigned short* oattn_t, const unsigned short* Wpb,
    const float* bpv, unsigned short* projb)
{
    stageE_body(blockIdx.x, threadIdx.x, oattn_t, Wpb, bpv, projb);
}

__global__ __launch_bounds__(256) void resize_kernel(
    const unsigned short* projb, const float* x,
    const float* gamma, float* out)
{
    stageF_body(blockIdx.x, threadIdx.x, projb, x, gamma, out);
}

// ===========================================================================
// Cooperative mega-kernel: same bodies, grid-stride, grid.sync boundaries
// ===========================================================================
__global__ __launch_bounds__(256, 2) void mega_kernel(
    const float* x, const float* Wq, const float* Wk, const float* Wv,
    const float* Wx, const float* Wy, const float* ab, const float* Wp,
    const float* bp, const float* gamma, float* out,
    unsigned short* posxb, unsigned short* posyb,
    unsigned short* Wb, unsigned short* Wpb,
    unsigned short* xs_t, unsigned short* qbuf,
    unsigned short* oattn_t, unsigned short* projb,
    float* vbuf, float* ek, uint4* vhat)
{
    cg::grid_group grid = cg::this_grid();
    int bid = blockIdx.x;
    int t = threadIdx.x;
    int stride = gridDim.x;

    for (int task = bid; task < 1064; task += stride) {
        __syncthreads();   // protect LDS reuse across iterations
        stageA_body(task, t, Wx, Wy, Wk, ab, Wq, Wv, Wp, x,
                    posxb, posyb, Wb, Wpb, xs_t);
    }
    grid.sync();

    for (int task = bid; task < 360; task += stride)
        stageB_body(task, t, xs_t, Wb, qbuf, vbuf, ek);
    grid.sync();

    for (int task = bid; task < 384; task += stride) {
        __syncthreads();
        stageC_body(task, t, vbuf, ek, vhat);
    }
    grid.sync();

    for (int task = bid; task < 576; task += stride) {
        __syncthreads();
        stageD_body(task, t, qbuf, posxb, posyb, vhat, oattn_t);
    }
    grid.sync();

    for (int task = bid; task < 144; task += stride)
        stageE_body(task, t, oattn_t, Wpb, bp, projb);
    grid.sync();

    for (int task = bid; task < 4608; task += stride)
        stageF_body(task, t, projb, x, gamma, out);
}

// ---------------------------------------------------------------------------
extern "C" void kernel_launch(void* const* d_in, const int* in_sizes, int n_in,
                              void* d_out, int out_size, void* d_ws, size_t ws_size,
                              hipStream_t stream)
{
    const float* x     = (const float*)d_in[0];
    const float* Wq    = (const float*)d_in[1];
    const float* Wk    = (const float*)d_in[2];
    const float* Wv    = (const float*)d_in[3];
    const float* Wx    = (const float*)d_in[4];
    const float* Wy    = (const float*)d_in[5];
    const float* ab    = (const float*)d_in[6];
    const float* Wp    = (const float*)d_in[7];
    const float* bp    = (const float*)d_in[8];
    const float* gamma = (const float*)d_in[9];
    float* out = (float*)d_out;

    unsigned short* posxb = (unsigned short*)d_ws;           // 8*96*32
    unsigned short* posyb  = posxb + 8 * 96 * 32;
    unsigned short* Wb     = posyb + 8 * 96 * 32;            // 640*256
    unsigned short* Wpb    = Wb + (size_t)640 * 256;         // 256*256
    unsigned short* xs_t   = Wpb + (size_t)256 * 256;        // 2*2304*256
    unsigned short* qbuf   = xs_t + (size_t)2 * NPOS * 256;  // 2*8*2304*32
    unsigned short* oattn_t= qbuf + (size_t)2 * NPOS * 256;  // 2*2304*256
    unsigned short* projb  = oattn_t + (size_t)2 * NPOS * 256; // 2*256*2304
    float* vbuf  = (float*)(projb + (size_t)2 * NPOS * 256); // 2*256*2304 fp32
    float* ek    = vbuf + (size_t)2 * 256 * NPOS;            // 16*2304
    uint4* vhat  = (uint4*)(ek + 16 * NPOS);                 // 16*24*576 uint4

    void* args[] = {
        (void*)&x, (void*)&Wq, (void*)&Wk, (void*)&Wv, (void*)&Wx, (void*)&Wy,
        (void*)&ab, (void*)&Wp, (void*)&bp, (void*)&gamma, (void*)&out,
        (void*)&posxb, (void*)&posyb, (void*)&Wb, (void*)&Wpb, (void*)&xs_t,
        (void*)&qbuf, (void*)&oattn_t, (void*)&projb, (void*)&vbuf, (void*)&ek,
        (void*)&vhat
    };
    hipError_t ce = hipLaunchCooperativeKernel((const void*)mega_kernel,
                                               dim3(512), dim3(256),
                                               args, 0, stream);
    if (ce != hipSuccess) {
        (void)hipGetLastError();   // clear sticky error, use fallback path
        hipLaunchKernelGGL(prep_extract_kernel, dim3(1064), dim3(256), 0, stream,
                           Wx, Wy, Wk, ab, Wq, Wv, Wp, x, posxb, posyb, Wb, Wpb, xs_t);
        hipLaunchKernelGGL(qkv_kernel, dim3(360), dim3(256), 0, stream,
                           xs_t, Wb, qbuf, vbuf, ek);
        hipLaunchKernelGGL(vhat_kernel, dim3(384), dim3(256), 0, stream,
                           vbuf, ek, vhat);
        hipLaunchKernelGGL(attn_kernel, dim3(576), dim3(256), 0, stream,
                           qbuf, posxb, posyb, vhat, oattn_t);
        hipLaunchKernelGGL(proj_kernel, dim3(144), dim3(256), 0, stream,
                           oattn_t, Wpb, bp, projb);
        hipLaunchKernelGGL(resize_kernel, dim3(4608), dim3(256), 0, stream,
                           projb, x, gamma, out);
    }
}

// Round 5
// 154.358 us; speedup vs baseline: 3.0388x; 3.0388x over previous
//
#include <hip/hip_runtime.h>
#include <hip/hip_bf16.h>
#include <math.h>

// Problem constants
#define NB 2
#define CC 256
#define NPOS 2304   // 48*48
#define NDELTA 95

typedef __attribute__((ext_vector_type(8))) short short8;
typedef __attribute__((ext_vector_type(4))) float floatx4;

__device__ inline unsigned short f2bf(float x) {
    unsigned int u = __float_as_uint(x);
    u = (u + 0x7FFFu + ((u >> 16) & 1u)) >> 16;
    return (unsigned short)u;
}
__device__ inline float bf2f(unsigned short h) {
    return __uint_as_float(((unsigned int)h) << 16);
}
__device__ inline unsigned int pk2(float a, float b) {
    return (unsigned int)f2bf(a) | ((unsigned int)f2bf(b) << 16);
}
__device__ inline unsigned int pkmul(unsigned int a, unsigned int b) {
    __hip_bfloat162 x = *(__hip_bfloat162*)&a;
    __hip_bfloat162 y = *(__hip_bfloat162*)&b;
    __hip_bfloat162 r = __hmul2(x, y);
    return *(unsigned int*)&r;
}

// ---------------------------------------------------------------------------
// Kernel 1: fused prep + extract. Grid 1064 (verbatim from verified 152.9us).
// ---------------------------------------------------------------------------
__global__ __launch_bounds__(256) void prep_extract_kernel(
    const float* __restrict__ Wx, const float* __restrict__ Wy,
    const float* __restrict__ Wk, const float* __restrict__ ab,
    const float* __restrict__ Wq, const float* __restrict__ Wv,
    const float* __restrict__ Wp, const float* __restrict__ x,
    unsigned short* __restrict__ posxb, unsigned short* __restrict__ posyb,
    unsigned short* __restrict__ Wb, unsigned short* __restrict__ Wpb,
    unsigned short* __restrict__ xs_t)
{
    __shared__ __align__(16) unsigned short Lt[64][264];
    int b = blockIdx.x;
    int t = threadIdx.x;
    if (b < NDELTA) {
        float* emb = (float*)&Lt[0][0];
        float delta = (float)(b - 47);
        if (t < 64) {
            float dim_inv = exp2f(-(float)t * 0.15571537944784511f); // log2(1000)/64
            float ang = 2.0f * delta * dim_inv;
            emb[t]      = sinf(ang);
            emb[t + 64] = cosf(ang);
        }
        __syncthreads();
        float sx = 0.f, sy = 0.f;
        const float* wxr = Wx + t * 128;
        const float* wyr = Wy + t * 128;
        for (int f = 0; f < 128; ++f) {
            float e = emb[f];
            sx += e * wxr[f];
            sy += e * wyr[f];
        }
        const float inv_sqrt2 = 0.70710678118654752440f;
        int g = t >> 5, d = t & 31;
        posxb[((size_t)g * 96 + b) * 32 + d] = f2bf(sx * inv_sqrt2);
        posyb[((size_t)g * 96 + b) * 32 + d] = f2bf(sy * inv_sqrt2);
    } else if (b == NDELTA) {
        int g = t >> 5, d = t & 31;
        posxb[((size_t)g * 96 + 95) * 32 + d] = 0;
        posyb[((size_t)g * 96 + 95) * 32 + d] = 0;
    } else if (b < 96 + 640) {
        int o = b - 96;
        float v = 0.f;
        if (o < 256)      v = Wq[o * 256 + t];
        else if (o < 512) v = Wv[(o - 256) * 256 + t];
        else if (o < 520) {
            int g = o - 512;
            float s = 0.f;
            for (int d = 0; d < 32; ++d)
                s += ab[g * 32 + d] * Wk[(g * 32 + d) * 256 + t];
            v = s;
        }
        Wb[(size_t)o * 256 + t] = f2bf(v);
    } else if (b < 992) {
        int o = b - 736;
        Wpb[(size_t)o * 256 + t] = f2bf(Wp[o * 256 + t]);
    } else {
        // --- extract: x[:, :, ::2, ::2] -> bf16 transposed ---
        int blk = b - 992;
        int pt = blk % 36;
        int n = blk / 36;
        int p0 = pt * 64;
        int cw = t >> 4;      // 0..15
        int pl = t & 15;

        for (int cc = 0; cc < 16; ++cc) {
            int c = cc * 16 + cw;
            const float* src = x + ((size_t)(n * 256 + c)) * (96 * 96);
            #pragma unroll
            for (int k = 0; k < 4; ++k) {
                int p = p0 + pl + k * 16;
                int i = p / 48, j = p - i * 48;
                Lt[pl + k * 16][c] = f2bf(src[(2 * i) * 96 + 2 * j]);
            }
        }
        __syncthreads();
        #pragma unroll
        for (int it = 0; it < 8; ++it) {
            int s = t + it * 256;
            int p = s >> 5, c8 = s & 31;
            uint4 v = *(const uint4*)&Lt[p][c8 * 8];
            *(uint4*)(xs_t + ((size_t)(n * NPOS + p0 + p)) * 256 + c8 * 8) = v;
        }
    }
}

// ---------------------------------------------------------------------------
// Kernel 2: Q/V/e_key projection — pure-MFMA, no LDS, no barriers.
// N=32 tiles for more blocks: grid (5, 144) = 720 blocks, 4 blocks/CU.
// ---------------------------------------------------------------------------
__global__ __launch_bounds__(256, 4) void qkv_kernel(
    const unsigned short* __restrict__ xs_t, const unsigned short* __restrict__ Wb,
    unsigned short* __restrict__ qbuf, float* __restrict__ vbuf,
    float* __restrict__ ek)
{
    int mT = blockIdx.x;           // 0..4
    int nT = blockIdx.y;           // 0..143
    int t = threadIdx.x;
    int wm = t >> 6, L = t & 63, l16 = L & 15, oct = L >> 4;
    int colBase = nT * 32;
    int n = colBase / NPOS;
    int p0 = colBase - n * NPOS;
    int o_w = mT * 128 + wm * 32;

    const unsigned short* A0 = Wb + (size_t)(o_w + l16) * 256 + oct * 8;
    const unsigned short* A1 = A0 + 16 * 256;
    const unsigned short* B0 = xs_t + ((size_t)(n * NPOS + p0 + l16)) * 256 + oct * 8;

    floatx4 acc[2][2] = {};
    #pragma unroll
    for (int kc = 0; kc < 8; ++kc) {
        int k0 = kc * 32;
        short8 a0 = *(const short8*)(A0 + k0);
        short8 a1 = *(const short8*)(A1 + k0);
        short8 b0 = *(const short8*)(B0 + k0);
        short8 b1 = *(const short8*)(B0 + 16 * 256 + k0);
        acc[0][0] = __builtin_amdgcn_mfma_f32_16x16x32_bf16(a0, b0, acc[0][0], 0, 0, 0);
        acc[0][1] = __builtin_amdgcn_mfma_f32_16x16x32_bf16(a0, b1, acc[0][1], 0, 0, 0);
        acc[1][0] = __builtin_amdgcn_mfma_f32_16x16x32_bf16(a1, b0, acc[1][0], 0, 0, 0);
        acc[1][1] = __builtin_amdgcn_mfma_f32_16x16x32_bf16(a1, b1, acc[1][1], 0, 0, 0);
    }

    if (o_w < 256) {
        #pragma unroll
        for (int af = 0; af < 2; ++af) {
            int ob = o_w + af * 16 + oct * 4;
            int g = ob >> 5, d0 = ob & 31;
            #pragma unroll
            for (int f = 0; f < 2; ++f) {
                int p = p0 + f * 16 + l16;
                uint2 w;
                w.x = pk2(acc[af][f][0], acc[af][f][1]);
                w.y = pk2(acc[af][f][2], acc[af][f][3]);
                *(uint2*)&qbuf[((size_t)(n * 8 + g) * NPOS + p) * 32 + d0] = w;
            }
        }
    } else if (o_w < 512) {
        #pragma unroll
        for (int af = 0; af < 2; ++af) {
            #pragma unroll
            for (int f = 0; f < 2; ++f) {
                int p = p0 + f * 16 + l16;
                #pragma unroll
                for (int r = 0; r < 4; ++r) {
                    int o = o_w + af * 16 + oct * 4 + r;
                    vbuf[((size_t)(n * 256 + (o - 256))) * NPOS + p] = acc[af][f][r];
                }
            }
        }
    } else {
        #pragma unroll
        for (int af = 0; af < 2; ++af) {
            #pragma unroll
            for (int f = 0; f < 2; ++f) {
                int p = p0 + f * 16 + l16;
                #pragma unroll
                for (int r = 0; r < 4; ++r) {
                    int o = o_w + af * 16 + oct * 4 + r;
                    if (o < 520)
                        ek[((size_t)(n * 8 + (o - 512))) * NPOS + p] = acc[af][f][r];
                }
            }
        }
    }
}

// ---------------------------------------------------------------------------
// Kernel 3: V̂ = exp(ek)*V in bf16 B-fragment order (verbatim verified).
// ---------------------------------------------------------------------------
__global__ __launch_bounds__(256) void vhat_kernel(
    const float* __restrict__ vbuf, const float* __restrict__ ek,
    uint4* __restrict__ vhat)
{
    int tile = blockIdx.x;   // 0..23
    int ng = blockIdx.y;     // 0..15
    int k0 = tile * 96;
    int t = threadIdx.x;
    const float* vb = vbuf + (size_t)ng * 32 * NPOS;
    uint4* out = vhat + ((size_t)ng * 24 + tile) * 576;

    __shared__ __align__(16) float Ae[96];
    if (t < 96) Ae[t] = __expf(ek[(size_t)ng * NPOS + k0 + t]);
    __syncthreads();

    for (int s = t; s < 576; s += 256) {
        int grp = s >> 6;
        int Ls = s & 63;
        int cc = grp / 3;
        int nn = grp - cc * 3;
        int koct = cc * 32 + ((Ls >> 4) << 3);
        uint4 w = make_uint4(0u, 0u, 0u, 0u);
        if (nn < 2) {
            int d = nn * 16 + (Ls & 15);
            const float* vp = vb + (size_t)d * NPOS + k0 + koct;
            const float* ap = Ae + koct;
            float4 v0 = *(const float4*)vp;
            float4 v1 = *(const float4*)(vp + 4);
            float4 a0 = *(const float4*)ap;
            float4 a1 = *(const float4*)(ap + 4);
            w.x = pk2(v0.x * a0.x, v0.y * a0.y);
            w.y = pk2(v0.z * a0.z, v0.w * a0.w);
            w.z = pk2(v1.x * a1.x, v1.y * a1.y);
            w.w = pk2(v1.z * a1.z, v1.w * a1.w);
        } else if ((Ls & 15) == 0) {
            const float* ap = Ae + koct;
            float4 a0 = *(const float4*)ap;
            float4 a1 = *(const float4*)(ap + 4);
            w.x = pk2(a0.x, a0.y);
            w.y = pk2(a0.z, a0.w);
            w.z = pk2(a1.x, a1.y);
            w.w = pk2(a1.z, a1.w);
        }
        out[s] = w;
    }
}

// ---------------------------------------------------------------------------
// Kernel 4: attention (verbatim verified r8 structure).
// ---------------------------------------------------------------------------
#define DO_TILE(BB, TT) do {                                                   \
    int u0_ = (TT) * 2;                                                        \
    unsigned int y0_ = Ys[qp * 50 + u0_];     y0_ |= y0_ << 16;                \
    unsigned int y1_ = Ys[qp * 50 + u0_ + 1]; y1_ |= y1_ << 16;                \
    unsigned int Yc0_ = y0_, Yc1_ = (o < 2) ? y0_ : y1_, Yc2_ = y1_;           \
    union { unsigned int u[4]; short8 s; } av_;                                \
    av_.u[0] = pkmul(Xp[0], Yc0_); av_.u[1] = pkmul(Xp[1], Yc0_);              \
    av_.u[2] = pkmul(Xp[2], Yc0_); av_.u[3] = pkmul(Xp[3], Yc0_);              \
    acc0 = __builtin_amdgcn_mfma_f32_16x16x32_bf16(av_.s, *(const short8*)&BB[0], acc0, 0, 0, 0); \
    acc1 = __builtin_amdgcn_mfma_f32_16x16x32_bf16(av_.s, *(const short8*)&BB[1], acc1, 0, 0, 0); \
    acc2 = __builtin_amdgcn_mfma_f32_16x16x32_bf16(av_.s, *(const short8*)&BB[2], acc2, 0, 0, 0); \
    av_.u[0] = pkmul(Xp[4], Yc1_); av_.u[1] = pkmul(Xp[5], Yc1_);              \
    av_.u[2] = pkmul(Xp[6], Yc1_); av_.u[3] = pkmul(Xp[7], Yc1_);              \
    acc0 = __builtin_amdgcn_mfma_f32_16x16x32_bf16(av_.s, *(const short8*)&BB[3], acc0, 0, 0, 0); \
    acc1 = __builtin_amdgcn_mfma_f32_16x16x32_bf16(av_.s, *(const short8*)&BB[4], acc1, 0, 0, 0); \
    acc2 = __builtin_amdgcn_mfma_f32_16x16x32_bf16(av_.s, *(const short8*)&BB[5], acc2, 0, 0, 0); \
    av_.u[0] = pkmul(Xp[8], Yc2_); av_.u[1] = pkmul(Xp[9], Yc2_);              \
    av_.u[2] = pkmul(Xp[10], Yc2_); av_.u[3] = pkmul(Xp[11], Yc2_);            \
    acc0 = __builtin_amdgcn_mfma_f32_16x16x32_bf16(av_.s, *(const short8*)&BB[6], acc0, 0, 0, 0); \
    acc1 = __builtin_amdgcn_mfma_f32_16x16x32_bf16(av_.s, *(const short8*)&BB[7], acc1, 0, 0, 0); \
    acc2 = __builtin_amdgcn_mfma_f32_16x16x32_bf16(av_.s, *(const short8*)&BB[8], acc2, 0, 0, 0); \
} while (0)

__global__ __launch_bounds__(256, 2) void attn_kernel(
    const unsigned short* __restrict__ qbuf, const unsigned short* __restrict__ posxb,
    const unsigned short* __restrict__ posyb, const uint4* __restrict__ vhat,
    unsigned short* __restrict__ oattn_t)
{
    __shared__ unsigned short Xs[64 * 50];
    __shared__ unsigned short Ys[64 * 50];
    __shared__ float linv_s[64];

    int blk = blockIdx.x;
    int qt = blk % 36;
    int ng = blk / 36;
    int nb = ng >> 3, g = ng & 7;
    int qbase = qt * 64;
    int t = threadIdx.x;
    int m = t >> 6, L = t & 63;
    int l16 = L & 15, oct = L >> 4;

    // ---- prologue: T = Q·pos^T via MFMA, X/Y = exp(T) into LDS ----
    {
        int qtile0 = qbase + m * 16;
        int hq = qtile0 / 48;
        int wq0 = qtile0 - hq * 48;
        short8 aq = *(const short8*)(qbuf +
            ((size_t)ng * NPOS + qtile0 + l16) * 32 + oct * 8);
        const unsigned short* pxg = posxb + (size_t)g * 96 * 32;
        const unsigned short* pyg = posyb + (size_t)g * 96 * 32;
        floatx4 zero = {0.f, 0.f, 0.f, 0.f};
        #pragma unroll
        for (int j = 0; j < 6; ++j) {
            int dl = j * 16 + l16;
            short8 bx = *(const short8*)(pxg + (size_t)dl * 32 + oct * 8);
            short8 by = *(const short8*)(pyg + (size_t)dl * 32 + oct * 8);
            floatx4 tx = __builtin_amdgcn_mfma_f32_16x16x32_bf16(aq, bx, zero, 0, 0, 0);
            floatx4 ty = __builtin_amdgcn_mfma_f32_16x16x32_bf16(aq, by, zero, 0, 0, 0);
            int u = hq + 47 - dl;
            bool uok = (u >= 0) && (u < 48);
            #pragma unroll
            for (int r = 0; r < 4; ++r) {
                int ql = oct * 4 + r;
                int v = wq0 + ql + 47 - dl;
                if (v >= 0 && v < 48)
                    Xs[(m * 16 + ql) * 50 + v] = f2bf(__expf(tx[r]));
                if (uok)
                    Ys[(m * 16 + ql) * 50 + u] = f2bf(__expf(ty[r]));
            }
        }
    }
    __syncthreads();

    int qp = m * 16 + l16;
    int o = oct;
    unsigned int Xp[12];
    #pragma unroll
    for (int c = 0; c < 3; ++c)
        #pragma unroll
        for (int jj = 0; jj < 4; ++jj) {
            int k = c * 32 + o * 8 + jj * 2;
            int v0 = (k < 48) ? k : k - 48;
            Xp[c * 4 + jj] = *(const unsigned int*)&Xs[qp * 50 + v0];
        }

    floatx4 acc0 = {0.f, 0.f, 0.f, 0.f};
    floatx4 acc1 = {0.f, 0.f, 0.f, 0.f};
    floatx4 acc2 = {0.f, 0.f, 0.f, 0.f};

    const uint4* vb = vhat + (size_t)ng * 24 * 576 + L;
    uint4 Abuf[9], Bbuf[9];
    #pragma unroll
    for (int gg = 0; gg < 9; ++gg) Abuf[gg] = vb[gg * 64];

    for (int tile = 0; tile < 24; tile += 2) {
        const uint4* sB = vb + (tile + 1) * 576;
        #pragma unroll
        for (int gg = 0; gg < 9; ++gg) Bbuf[gg] = sB[gg * 64];
        DO_TILE(Abuf, tile);
        if (tile + 2 < 24) {
            const uint4* sA = vb + (tile + 2) * 576;
            #pragma unroll
            for (int gg = 0; gg < 9; ++gg) Abuf[gg] = sA[gg * 64];
        }
        DO_TILE(Bbuf, tile + 1);
    }

    if ((L & 15) == 0) {
        int qc = m * 16 + (L >> 4) * 4;
        #pragma unroll
        for (int r = 0; r < 4; ++r)
            linv_s[qc + r] = 1.0f / acc2[r];
    }
    __syncthreads();
    {
        int qc = m * 16 + (L >> 4) * 4;
        int d0 = L & 15;
        #pragma unroll
        for (int r = 0; r < 4; ++r) {
            float lir = linv_s[qc + r];
            size_t row = ((size_t)nb * NPOS + qbase + qc + r) * 256;
            oattn_t[row + g * 32 + d0]      = f2bf(acc0[r] * lir);
            oattn_t[row + g * 32 + 16 + d0] = f2bf(acc1[r] * lir);
        }
    }
}

// ---------------------------------------------------------------------------
// Kernel 5: output projection — N=32 tiles: grid (2, 144) = 288 blocks.
// ---------------------------------------------------------------------------
__global__ __launch_bounds__(256, 4) void proj_kernel(
    const unsigned short* __restrict__ oattn_t, const unsigned short* __restrict__ Wpb,
    const float* __restrict__ bpv, unsigned short* __restrict__ projb)
{
    int mT = blockIdx.x;           // 0..1
    int nT = blockIdx.y;           // 0..143
    int t = threadIdx.x;
    int wm = t >> 6, L = t & 63, l16 = L & 15, oct = L >> 4;
    int colBase = nT * 32;
    int n = colBase / NPOS;
    int p0 = colBase - n * NPOS;
    int o_w = mT * 128 + wm * 32;

    const unsigned short* A0 = Wpb + (size_t)(o_w + l16) * 256 + oct * 8;
    const unsigned short* A1 = A0 + 16 * 256;
    const unsigned short* B0 = oattn_t + ((size_t)(n * NPOS + p0 + l16)) * 256 + oct * 8;

    floatx4 acc[2][2] = {};
    #pragma unroll
    for (int kc = 0; kc < 8; ++kc) {
        int k0 = kc * 32;
        short8 a0 = *(const short8*)(A0 + k0);
        short8 a1 = *(const short8*)(A1 + k0);
        short8 b0 = *(const short8*)(B0 + k0);
        short8 b1 = *(const short8*)(B0 + 16 * 256 + k0);
        acc[0][0] = __builtin_amdgcn_mfma_f32_16x16x32_bf16(a0, b0, acc[0][0], 0, 0, 0);
        acc[0][1] = __builtin_amdgcn_mfma_f32_16x16x32_bf16(a0, b1, acc[0][1], 0, 0, 0);
        acc[1][0] = __builtin_amdgcn_mfma_f32_16x16x32_bf16(a1, b0, acc[1][0], 0, 0, 0);
        acc[1][1] = __builtin_amdgcn_mfma_f32_16x16x32_bf16(a1, b1, acc[1][1], 0, 0, 0);
    }

    #pragma unroll
    for (int af = 0; af < 2; ++af) {
        #pragma unroll
        for (int f = 0; f < 2; ++f) {
            int p = p0 + f * 16 + l16;
            #pragma unroll
            for (int r = 0; r < 4; ++r) {
                int o = o_w + af * 16 + oct * 4 + r;
                projb[((size_t)(n * 256 + o)) * NPOS + p] = f2bf(acc[af][f][r] + bpv[o]);
            }
        }
    }
}

// ---------------------------------------------------------------------------
// Kernel 6: bilinear 48->96 upsample + residual, 4 px/thread (verbatim).
// ---------------------------------------------------------------------------
__global__ __launch_bounds__(256) void resize_kernel(
    const unsigned short* __restrict__ projb, const float* __restrict__ x,
    const float* __restrict__ gamma, float* __restrict__ out)
{
    int idx4 = blockIdx.x * 256 + threadIdx.x;   // each handles 4 J
    int J0 = (idx4 % 24) * 4;
    int tmp = idx4 / 24;
    int I = tmp % 96;
    int nc = tmp / 96;

    int jr = I >> 1;
    int r0, r1; float w0, w1;
    if ((I & 1) == 0) { r0 = (jr > 0) ? jr - 1 : 0; r1 = jr; w0 = 0.25f; w1 = 0.75f; }
    else              { r0 = jr; r1 = (jr < 47) ? jr + 1 : 47; w0 = 0.75f; w1 = 0.25f; }

    const unsigned short* P = projb + (size_t)nc * NPOS;
    size_t base = ((size_t)nc * 96 + I) * 96 + J0;
    float4 xv = *(const float4*)(x + base);
    float gm = gamma[0];
    float4 ov;
    #pragma unroll
    for (int k = 0; k < 4; ++k) {
        int J = J0 + k;
        int jc = J >> 1;
        int c0, c1; float u0, u1;
        if ((J & 1) == 0) { c0 = (jc > 0) ? jc - 1 : 0; c1 = jc; u0 = 0.25f; u1 = 0.75f; }
        else              { c0 = jc; c1 = (jc < 47) ? jc + 1 : 47; u0 = 0.75f; u1 = 0.25f; }
        float v = w0 * (u0 * bf2f(P[r0 * 48 + c0]) + u1 * bf2f(P[r0 * 48 + c1])) +
                  w1 * (u0 * bf2f(P[r1 * 48 + c0]) + u1 * bf2f(P[r1 * 48 + c1]));
        float xr = (k == 0) ? xv.x : (k == 1) ? xv.y : (k == 2) ? xv.z : xv.w;
        float o = gm * v + xr;
        if (k == 0) ov.x = o; else if (k == 1) ov.y = o; else if (k == 2) ov.z = o; else ov.w = o;
    }
    *(float4*)(out + base) = ov;
}

// ---------------------------------------------------------------------------
extern "C" void kernel_launch(void* const* d_in, const int* in_sizes, int n_in,
                              void* d_out, int out_size, void* d_ws, size_t ws_size,
                              hipStream_t stream)
{
    const float* x     = (const float*)d_in[0];
    const float* Wq    = (const float*)d_in[1];
    const float* Wk    = (const float*)d_in[2];
    const float* Wv    = (const float*)d_in[3];
    const float* Wx    = (const float*)d_in[4];
    const float* Wy    = (const float*)d_in[5];
    const float* ab    = (const float*)d_in[6];
    const float* Wp    = (const float*)d_in[7];
    const float* bp    = (const float*)d_in[8];
    const float* gamma = (const float*)d_in[9];
    float* out = (float*)d_out;

    unsigned short* posxb = (unsigned short*)d_ws;           // 8*96*32
    unsigned short* posyb  = posxb + 8 * 96 * 32;
    unsigned short* Wb     = posyb + 8 * 96 * 32;            // 640*256
    unsigned short* Wpb    = Wb + (size_t)640 * 256;         // 256*256
    unsigned short* xs_t   = Wpb + (size_t)256 * 256;        // 2*2304*256
    unsigned short* qbuf   = xs_t + (size_t)2 * NPOS * 256;  // 2*8*2304*32
    unsigned short* oattn_t= qbuf + (size_t)2 * NPOS * 256;  // 2*2304*256
    unsigned short* projb  = oattn_t + (size_t)2 * NPOS * 256; // 2*256*2304
    float* vbuf  = (float*)(projb + (size_t)2 * NPOS * 256); // 2*256*2304 fp32
    float* ek    = vbuf + (size_t)2 * 256 * NPOS;            // 16*2304
    uint4* vhat  = (uint4*)(ek + 16 * NPOS);                 // 16*24*576 uint4

    hipLaunchKernelGGL(prep_extract_kernel, dim3(1064), dim3(256), 0, stream,
                       Wx, Wy, Wk, ab, Wq, Wv, Wp, x, posxb, posyb, Wb, Wpb, xs_t);
    hipLaunchKernelGGL(qkv_kernel, dim3(5, 144), dim3(256), 0, stream,
                       xs_t, Wb, qbuf, vbuf, ek);
    hipLaunchKernelGGL(vhat_kernel, dim3(24, 16), dim3(256), 0, stream,
                       vbuf, ek, vhat);
    hipLaunchKernelGGL(attn_kernel, dim3(576), dim3(256), 0, stream,
                       qbuf, posxb, posyb, vhat, oattn_t);
    hipLaunchKernelGGL(proj_kernel, dim3(2, 144), dim3(256), 0, stream,
                       oattn_t, Wpb, bp, projb);
    hipLaunchKernelGGL(resize_kernel, dim3((2 * 256 * 96 * 96) / (256 * 4)), dim3(256), 0, stream,
                       projb, x, gamma, out);
}

// Round 6
// 150.269 us; speedup vs baseline: 3.1214x; 1.0272x over previous
//
#include <hip/hip_runtime.h>
#include <hip/hip_bf16.h>
#include <math.h>

// Problem constants
#define NB 2
#define CC 256
#define NPOS 2304   // 48*48
#define NDELTA 95

typedef __attribute__((ext_vector_type(8))) short short8;
typedef __attribute__((ext_vector_type(4))) float floatx4;

__device__ inline unsigned short f2bf(float x) {
    unsigned int u = __float_as_uint(x);
    u = (u + 0x7FFFu + ((u >> 16) & 1u)) >> 16;
    return (unsigned short)u;
}
__device__ inline float bf2f(unsigned short h) {
    return __uint_as_float(((unsigned int)h) << 16);
}
__device__ inline unsigned int pk2(float a, float b) {
    return (unsigned int)f2bf(a) | ((unsigned int)f2bf(b) << 16);
}
__device__ inline unsigned int pkmul(unsigned int a, unsigned int b) {
    __hip_bfloat162 x = *(__hip_bfloat162*)&a;
    __hip_bfloat162 y = *(__hip_bfloat162*)&b;
    __hip_bfloat162 r = __hmul2(x, y);
    return *(unsigned int*)&r;
}

// ---------------------------------------------------------------------------
// Kernel 1: fused prep + extract. Grid 1064 (verbatim verified).
// ---------------------------------------------------------------------------
__global__ __launch_bounds__(256) void prep_extract_kernel(
    const float* __restrict__ Wx, const float* __restrict__ Wy,
    const float* __restrict__ Wk, const float* __restrict__ ab,
    const float* __restrict__ Wq, const float* __restrict__ Wv,
    const float* __restrict__ Wp, const float* __restrict__ x,
    unsigned short* __restrict__ posxb, unsigned short* __restrict__ posyb,
    unsigned short* __restrict__ Wb, unsigned short* __restrict__ Wpb,
    unsigned short* __restrict__ xs_t)
{
    __shared__ __align__(16) unsigned short Lt[64][264];
    int b = blockIdx.x;
    int t = threadIdx.x;
    if (b < NDELTA) {
        float* emb = (float*)&Lt[0][0];
        float delta = (float)(b - 47);
        if (t < 64) {
            float dim_inv = exp2f(-(float)t * 0.15571537944784511f); // log2(1000)/64
            float ang = 2.0f * delta * dim_inv;
            emb[t]      = sinf(ang);
            emb[t + 64] = cosf(ang);
        }
        __syncthreads();
        float sx = 0.f, sy = 0.f;
        const float* wxr = Wx + t * 128;
        const float* wyr = Wy + t * 128;
        for (int f = 0; f < 128; ++f) {
            float e = emb[f];
            sx += e * wxr[f];
            sy += e * wyr[f];
        }
        const float inv_sqrt2 = 0.70710678118654752440f;
        int g = t >> 5, d = t & 31;
        posxb[((size_t)g * 96 + b) * 32 + d] = f2bf(sx * inv_sqrt2);
        posyb[((size_t)g * 96 + b) * 32 + d] = f2bf(sy * inv_sqrt2);
    } else if (b == NDELTA) {
        int g = t >> 5, d = t & 31;
        posxb[((size_t)g * 96 + 95) * 32 + d] = 0;
        posyb[((size_t)g * 96 + 95) * 32 + d] = 0;
    } else if (b < 96 + 640) {
        int o = b - 96;
        float v = 0.f;
        if (o < 256)      v = Wq[o * 256 + t];
        else if (o < 512) v = Wv[(o - 256) * 256 + t];
        else if (o < 520) {
            int g = o - 512;
            float s = 0.f;
            for (int d = 0; d < 32; ++d)
                s += ab[g * 32 + d] * Wk[(g * 32 + d) * 256 + t];
            v = s;
        }
        Wb[(size_t)o * 256 + t] = f2bf(v);
    } else if (b < 992) {
        int o = b - 736;
        Wpb[(size_t)o * 256 + t] = f2bf(Wp[o * 256 + t]);
    } else {
        // --- extract: x[:, :, ::2, ::2] -> bf16 transposed ---
        int blk = b - 992;
        int pt = blk % 36;
        int n = blk / 36;
        int p0 = pt * 64;
        int cw = t >> 4;      // 0..15
        int pl = t & 15;

        for (int cc = 0; cc < 16; ++cc) {
            int c = cc * 16 + cw;
            const float* src = x + ((size_t)(n * 256 + c)) * (96 * 96);
            #pragma unroll
            for (int k = 0; k < 4; ++k) {
                int p = p0 + pl + k * 16;
                int i = p / 48, j = p - i * 48;
                Lt[pl + k * 16][c] = f2bf(src[(2 * i) * 96 + 2 * j]);
            }
        }
        __syncthreads();
        #pragma unroll
        for (int it = 0; it < 8; ++it) {
            int s = t + it * 256;
            int p = s >> 5, c8 = s & 31;
            uint4 v = *(const uint4*)&Lt[p][c8 * 8];
            *(uint4*)(xs_t + ((size_t)(n * NPOS + p0 + p)) * 256 + c8 * 8) = v;
        }
    }
}

// ---------------------------------------------------------------------------
// Kernel 2: fused Q projection + V-hat. Grid (4, 72).
//   mT 0,1: Q rows (o 0..255) -> qbuf, verbatim R2 path.
//   mT 2,3: V rows; wave wm owns head g=(mT-2)*4+wm. Extra broadcast-A MFMA
//     chain computes ek[g][p] (all 16 output rows identical). e=exp(ek) in
//     register; products staged bf16 in per-wave LDS [33][72]; emitted as
//     attention-ready vhat uint4 fragments (bit-identical to old vhat path).
// ---------------------------------------------------------------------------
__global__ __launch_bounds__(256, 2) void qkvh_kernel(
    const unsigned short* __restrict__ xs_t, const unsigned short* __restrict__ Wb,
    unsigned short* __restrict__ qbuf, uint4* __restrict__ vhat)
{
    __shared__ __align__(16) unsigned short Vt[4][33][72];
    int mT = blockIdx.x;           // 0..3
    int nT = blockIdx.y;           // 0..71
    int t = threadIdx.x;
    int wm = t >> 6, L = t & 63, l16 = L & 15, oct = L >> 4;
    int colBase = nT * 64;
    int n = colBase / NPOS;
    int p0 = colBase - n * NPOS;
    int o_w = mT * 128 + wm * 32;
    bool isV = (mT >= 2);
    int gv = (mT & 1) * 4 + wm;    // head for v-path (mT=2 -> 0..3, mT=3 -> 4..7)

    const unsigned short* A0 = Wb + (size_t)(o_w + l16) * 256 + oct * 8;
    const unsigned short* A1 = A0 + 16 * 256;
    const unsigned short* AE = Wb + (size_t)(512 + gv) * 256 + oct * 8;
    const unsigned short* B0 = xs_t + ((size_t)(n * NPOS + p0 + l16)) * 256 + oct * 8;

    floatx4 acc[2][4] = {};
    floatx4 accE[4] = {};
    #pragma unroll
    for (int kc = 0; kc < 8; ++kc) {
        int k0 = kc * 32;
        short8 a0 = *(const short8*)(A0 + k0);
        short8 a1 = *(const short8*)(A1 + k0);
        short8 b0 = *(const short8*)(B0 + k0);
        short8 b1 = *(const short8*)(B0 + 16 * 256 + k0);
        short8 b2 = *(const short8*)(B0 + 32 * 256 + k0);
        short8 b3 = *(const short8*)(B0 + 48 * 256 + k0);
        acc[0][0] = __builtin_amdgcn_mfma_f32_16x16x32_bf16(a0, b0, acc[0][0], 0, 0, 0);
        acc[0][1] = __builtin_amdgcn_mfma_f32_16x16x32_bf16(a0, b1, acc[0][1], 0, 0, 0);
        acc[0][2] = __builtin_amdgcn_mfma_f32_16x16x32_bf16(a0, b2, acc[0][2], 0, 0, 0);
        acc[0][3] = __builtin_amdgcn_mfma_f32_16x16x32_bf16(a0, b3, acc[0][3], 0, 0, 0);
        acc[1][0] = __builtin_amdgcn_mfma_f32_16x16x32_bf16(a1, b0, acc[1][0], 0, 0, 0);
        acc[1][1] = __builtin_amdgcn_mfma_f32_16x16x32_bf16(a1, b1, acc[1][1], 0, 0, 0);
        acc[1][2] = __builtin_amdgcn_mfma_f32_16x16x32_bf16(a1, b2, acc[1][2], 0, 0, 0);
        acc[1][3] = __builtin_amdgcn_mfma_f32_16x16x32_bf16(a1, b3, acc[1][3], 0, 0, 0);
        if (isV) {
            short8 ae = *(const short8*)(AE + k0);
            accE[0] = __builtin_amdgcn_mfma_f32_16x16x32_bf16(ae, b0, accE[0], 0, 0, 0);
            accE[1] = __builtin_amdgcn_mfma_f32_16x16x32_bf16(ae, b1, accE[1], 0, 0, 0);
            accE[2] = __builtin_amdgcn_mfma_f32_16x16x32_bf16(ae, b2, accE[2], 0, 0, 0);
            accE[3] = __builtin_amdgcn_mfma_f32_16x16x32_bf16(ae, b3, accE[3], 0, 0, 0);
        }
    }

    if (!isV) {
        // ---- Q epilogue: packed uint2 stores into qbuf ----
        #pragma unroll
        for (int af = 0; af < 2; ++af) {
            int ob = o_w + af * 16 + oct * 4;
            int gq = ob >> 5, d0 = ob & 31;
            #pragma unroll
            for (int f = 0; f < 4; ++f) {
                int p = p0 + f * 16 + l16;
                uint2 w;
                w.x = pk2(acc[af][f][0], acc[af][f][1]);
                w.y = pk2(acc[af][f][2], acc[af][f][3]);
                *(uint2*)&qbuf[((size_t)(n * 8 + gq) * NPOS + p) * 32 + d0] = w;
            }
        }
    } else {
        // ---- V-hat epilogue ----
        // stage products (and exp row) as bf16 into this wave's LDS slice
        #pragma unroll
        for (int f = 0; f < 4; ++f) {
            float e = __expf(accE[f][0]);   // all 4 row-copies identical
            #pragma unroll
            for (int af = 0; af < 2; ++af)
                #pragma unroll
                for (int r = 0; r < 4; ++r)
                    Vt[wm][af * 16 + oct * 4 + r][f * 16 + l16] =
                        f2bf(acc[af][f][r] * e);
            if (oct == 0)
                Vt[wm][32][f * 16 + l16] = f2bf(e);
        }
        __syncthreads();

        // emit vhat uint4 fragments for the 8 k-octets this block owns
        int i = L >> 3, j = L & 7;
        int K = p0 + 8 * i;                 // global k within image
        int tile = K / 96;
        int rem = K - tile * 96;
        int cc = rem >> 5;
        int lhi = (rem & 31) >> 3;          // (Ls >> 4) slot
        uint4* vout = vhat + ((size_t)(n * 8 + gv) * 24 + tile) * 576;
        #pragma unroll
        for (int mm = 0; mm < 4; ++mm) {
            int d = j + 8 * mm;
            int nn = d >> 4;
            int Ls = lhi * 16 + (d & 15);
            uint4 w = *(const uint4*)&Vt[wm][d][8 * i];
            vout[(cc * 3 + nn) * 64 + Ls] = w;
        }
        // A-row (pure exp) slots: slot 0 real, 1..15 zero
        {
            uint4 wa = (j == 0) ? *(const uint4*)&Vt[wm][32][8 * i]
                                : make_uint4(0u, 0u, 0u, 0u);
            vout[(cc * 3 + 2) * 64 + lhi * 16 + j] = wa;
            vout[(cc * 3 + 2) * 64 + lhi * 16 + j + 8] = make_uint4(0u, 0u, 0u, 0u);
        }
    }
}

// ---------------------------------------------------------------------------
// Kernel 3: attention (verbatim verified r8 structure).
// ---------------------------------------------------------------------------
#define DO_TILE(BB, TT) do {                                                   \
    int u0_ = (TT) * 2;                                                        \
    unsigned int y0_ = Ys[qp * 50 + u0_];     y0_ |= y0_ << 16;                \
    unsigned int y1_ = Ys[qp * 50 + u0_ + 1]; y1_ |= y1_ << 16;                \
    unsigned int Yc0_ = y0_, Yc1_ = (o < 2) ? y0_ : y1_, Yc2_ = y1_;           \
    union { unsigned int u[4]; short8 s; } av_;                                \
    av_.u[0] = pkmul(Xp[0], Yc0_); av_.u[1] = pkmul(Xp[1], Yc0_);              \
    av_.u[2] = pkmul(Xp[2], Yc0_); av_.u[3] = pkmul(Xp[3], Yc0_);              \
    acc0 = __builtin_amdgcn_mfma_f32_16x16x32_bf16(av_.s, *(const short8*)&BB[0], acc0, 0, 0, 0); \
    acc1 = __builtin_amdgcn_mfma_f32_16x16x32_bf16(av_.s, *(const short8*)&BB[1], acc1, 0, 0, 0); \
    acc2 = __builtin_amdgcn_mfma_f32_16x16x32_bf16(av_.s, *(const short8*)&BB[2], acc2, 0, 0, 0); \
    av_.u[0] = pkmul(Xp[4], Yc1_); av_.u[1] = pkmul(Xp[5], Yc1_);              \
    av_.u[2] = pkmul(Xp[6], Yc1_); av_.u[3] = pkmul(Xp[7], Yc1_);              \
    acc0 = __builtin_amdgcn_mfma_f32_16x16x32_bf16(av_.s, *(const short8*)&BB[3], acc0, 0, 0, 0); \
    acc1 = __builtin_amdgcn_mfma_f32_16x16x32_bf16(av_.s, *(const short8*)&BB[4], acc1, 0, 0, 0); \
    acc2 = __builtin_amdgcn_mfma_f32_16x16x32_bf16(av_.s, *(const short8*)&BB[5], acc2, 0, 0, 0); \
    av_.u[0] = pkmul(Xp[8], Yc2_); av_.u[1] = pkmul(Xp[9], Yc2_);              \
    av_.u[2] = pkmul(Xp[10], Yc2_); av_.u[3] = pkmul(Xp[11], Yc2_);            \
    acc0 = __builtin_amdgcn_mfma_f32_16x16x32_bf16(av_.s, *(const short8*)&BB[6], acc0, 0, 0, 0); \
    acc1 = __builtin_amdgcn_mfma_f32_16x16x32_bf16(av_.s, *(const short8*)&BB[7], acc1, 0, 0, 0); \
    acc2 = __builtin_amdgcn_mfma_f32_16x16x32_bf16(av_.s, *(const short8*)&BB[8], acc2, 0, 0, 0); \
} while (0)

__global__ __launch_bounds__(256, 2) void attn_kernel(
    const unsigned short* __restrict__ qbuf, const unsigned short* __restrict__ posxb,
    const unsigned short* __restrict__ posyb, const uint4* __restrict__ vhat,
    unsigned short* __restrict__ oattn_t)
{
    __shared__ unsigned short Xs[64 * 50];
    __shared__ unsigned short Ys[64 * 50];
    __shared__ float linv_s[64];

    int blk = blockIdx.x;
    int qt = blk % 36;
    int ng = blk / 36;
    int nb = ng >> 3, g = ng & 7;
    int qbase = qt * 64;
    int t = threadIdx.x;
    int m = t >> 6, L = t & 63;
    int l16 = L & 15, oct = L >> 4;

    // ---- prologue: T = Q·pos^T via MFMA, X/Y = exp(T) into LDS ----
    {
        int qtile0 = qbase + m * 16;
        int hq = qtile0 / 48;
        int wq0 = qtile0 - hq * 48;
        short8 aq = *(const short8*)(qbuf +
            ((size_t)ng * NPOS + qtile0 + l16) * 32 + oct * 8);
        const unsigned short* pxg = posxb + (size_t)g * 96 * 32;
        const unsigned short* pyg = posyb + (size_t)g * 96 * 32;
        floatx4 zero = {0.f, 0.f, 0.f, 0.f};
        #pragma unroll
        for (int j = 0; j < 6; ++j) {
            int dl = j * 16 + l16;
            short8 bx = *(const short8*)(pxg + (size_t)dl * 32 + oct * 8);
            short8 by = *(const short8*)(pyg + (size_t)dl * 32 + oct * 8);
            floatx4 tx = __builtin_amdgcn_mfma_f32_16x16x32_bf16(aq, bx, zero, 0, 0, 0);
            floatx4 ty = __builtin_amdgcn_mfma_f32_16x16x32_bf16(aq, by, zero, 0, 0, 0);
            int u = hq + 47 - dl;
            bool uok = (u >= 0) && (u < 48);
            #pragma unroll
            for (int r = 0; r < 4; ++r) {
                int ql = oct * 4 + r;
                int v = wq0 + ql + 47 - dl;
                if (v >= 0 && v < 48)
                    Xs[(m * 16 + ql) * 50 + v] = f2bf(__expf(tx[r]));
                if (uok)
                    Ys[(m * 16 + ql) * 50 + u] = f2bf(__expf(ty[r]));
            }
        }
    }
    __syncthreads();

    int qp = m * 16 + l16;
    int o = oct;
    unsigned int Xp[12];
    #pragma unroll
    for (int c = 0; c < 3; ++c)
        #pragma unroll
        for (int jj = 0; jj < 4; ++jj) {
            int k = c * 32 + o * 8 + jj * 2;
            int v0 = (k < 48) ? k : k - 48;
            Xp[c * 4 + jj] = *(const unsigned int*)&Xs[qp * 50 + v0];
        }

    floatx4 acc0 = {0.f, 0.f, 0.f, 0.f};
    floatx4 acc1 = {0.f, 0.f, 0.f, 0.f};
    floatx4 acc2 = {0.f, 0.f, 0.f, 0.f};

    const uint4* vb = vhat + (size_t)ng * 24 * 576 + L;
    uint4 Abuf[9], Bbuf[9];
    #pragma unroll
    for (int gg = 0; gg < 9; ++gg) Abuf[gg] = vb[gg * 64];

    for (int tile = 0; tile < 24; tile += 2) {
        const uint4* sB = vb + (tile + 1) * 576;
        #pragma unroll
        for (int gg = 0; gg < 9; ++gg) Bbuf[gg] = sB[gg * 64];
        DO_TILE(Abuf, tile);
        if (tile + 2 < 24) {
            const uint4* sA = vb + (tile + 2) * 576;
            #pragma unroll
            for (int gg = 0; gg < 9; ++gg) Abuf[gg] = sA[gg * 64];
        }
        DO_TILE(Bbuf, tile + 1);
    }

    if ((L & 15) == 0) {
        int qc = m * 16 + (L >> 4) * 4;
        #pragma unroll
        for (int r = 0; r < 4; ++r)
            linv_s[qc + r] = 1.0f / acc2[r];
    }
    __syncthreads();
    {
        int qc = m * 16 + (L >> 4) * 4;
        int d0 = L & 15;
        #pragma unroll
        for (int r = 0; r < 4; ++r) {
            float lir = linv_s[qc + r];
            size_t row = ((size_t)nb * NPOS + qbase + qc + r) * 256;
            oattn_t[row + g * 32 + d0]      = f2bf(acc0[r] * lir);
            oattn_t[row + g * 32 + 16 + d0] = f2bf(acc1[r] * lir);
        }
    }
}

// ---------------------------------------------------------------------------
// Kernel 4: output projection — verbatim R2 (grid (2,72), N=64).
// ---------------------------------------------------------------------------
__global__ __launch_bounds__(256, 2) void proj_kernel(
    const unsigned short* __restrict__ oattn_t, const unsigned short* __restrict__ Wpb,
    const float* __restrict__ bpv, unsigned short* __restrict__ projb)
{
    int mT = blockIdx.x;           // 0..1
    int nT = blockIdx.y;           // 0..71
    int t = threadIdx.x;
    int wm = t >> 6, L = t & 63, l16 = L & 15, oct = L >> 4;
    int colBase = nT * 64;
    int n = colBase / NPOS;
    int p0 = colBase - n * NPOS;
    int o_w = mT * 128 + wm * 32;

    const unsigned short* A0 = Wpb + (size_t)(o_w + l16) * 256 + oct * 8;
    const unsigned short* A1 = A0 + 16 * 256;
    const unsigned short* B0 = oattn_t + ((size_t)(n * NPOS + p0 + l16)) * 256 + oct * 8;

    floatx4 acc[2][4] = {};
    #pragma unroll
    for (int kc = 0; kc < 8; ++kc) {
        int k0 = kc * 32;
        short8 a0 = *(const short8*)(A0 + k0);
        short8 a1 = *(const short8*)(A1 + k0);
        short8 b0 = *(const short8*)(B0 + k0);
        short8 b1 = *(const short8*)(B0 + 16 * 256 + k0);
        short8 b2 = *(const short8*)(B0 + 32 * 256 + k0);
        short8 b3 = *(const short8*)(B0 + 48 * 256 + k0);
        acc[0][0] = __builtin_amdgcn_mfma_f32_16x16x32_bf16(a0, b0, acc[0][0], 0, 0, 0);
        acc[0][1] = __builtin_amdgcn_mfma_f32_16x16x32_bf16(a0, b1, acc[0][1], 0, 0, 0);
        acc[0][2] = __builtin_amdgcn_mfma_f32_16x16x32_bf16(a0, b2, acc[0][2], 0, 0, 0);
        acc[0][3] = __builtin_amdgcn_mfma_f32_16x16x32_bf16(a0, b3, acc[0][3], 0, 0, 0);
        acc[1][0] = __builtin_amdgcn_mfma_f32_16x16x32_bf16(a1, b0, acc[1][0], 0, 0, 0);
        acc[1][1] = __builtin_amdgcn_mfma_f32_16x16x32_bf16(a1, b1, acc[1][1], 0, 0, 0);
        acc[1][2] = __builtin_amdgcn_mfma_f32_16x16x32_bf16(a1, b2, acc[1][2], 0, 0, 0);
        acc[1][3] = __builtin_amdgcn_mfma_f32_16x16x32_bf16(a1, b3, acc[1][3], 0, 0, 0);
    }

    #pragma unroll
    for (int af = 0; af < 2; ++af) {
        #pragma unroll
        for (int f = 0; f < 4; ++f) {
            int p = p0 + f * 16 + l16;
            #pragma unroll
            for (int r = 0; r < 4; ++r) {
                int o = o_w + af * 16 + oct * 4 + r;
                projb[((size_t)(n * 256 + o)) * NPOS + p] = f2bf(acc[af][f][r] + bpv[o]);
            }
        }
    }
}

// ---------------------------------------------------------------------------
// Kernel 5: bilinear 48->96 upsample + residual, 4 px/thread (verbatim).
// ---------------------------------------------------------------------------
__global__ __launch_bounds__(256) void resize_kernel(
    const unsigned short* __restrict__ projb, const float* __restrict__ x,
    const float* __restrict__ gamma, float* __restrict__ out)
{
    int idx4 = blockIdx.x * 256 + threadIdx.x;   // each handles 4 J
    int J0 = (idx4 % 24) * 4;
    int tmp = idx4 / 24;
    int I = tmp % 96;
    int nc = tmp / 96;

    int jr = I >> 1;
    int r0, r1; float w0, w1;
    if ((I & 1) == 0) { r0 = (jr > 0) ? jr - 1 : 0; r1 = jr; w0 = 0.25f; w1 = 0.75f; }
    else              { r0 = jr; r1 = (jr < 47) ? jr + 1 : 47; w0 = 0.75f; w1 = 0.25f; }

    const unsigned short* P = projb + (size_t)nc * NPOS;
    size_t base = ((size_t)nc * 96 + I) * 96 + J0;
    float4 xv = *(const float4*)(x + base);
    float gm = gamma[0];
    float4 ov;
    #pragma unroll
    for (int k = 0; k < 4; ++k) {
        int J = J0 + k;
        int jc = J >> 1;
        int c0, c1; float u0, u1;
        if ((J & 1) == 0) { c0 = (jc > 0) ? jc - 1 : 0; c1 = jc; u0 = 0.25f; u1 = 0.75f; }
        else              { c0 = jc; c1 = (jc < 47) ? jc + 1 : 47; u0 = 0.75f; u1 = 0.25f; }
        float v = w0 * (u0 * bf2f(P[r0 * 48 + c0]) + u1 * bf2f(P[r0 * 48 + c1])) +
                  w1 * (u0 * bf2f(P[r1 * 48 + c0]) + u1 * bf2f(P[r1 * 48 + c1]));
        float xr = (k == 0) ? xv.x : (k == 1) ? xv.y : (k == 2) ? xv.z : xv.w;
        float o = gm * v + xr;
        if (k == 0) ov.x = o; else if (k == 1) ov.y = o; else if (k == 2) ov.z = o; else ov.w = o;
    }
    *(float4*)(out + base) = ov;
}

// ---------------------------------------------------------------------------
extern "C" void kernel_launch(void* const* d_in, const int* in_sizes, int n_in,
                              void* d_out, int out_size, void* d_ws, size_t ws_size,
                              hipStream_t stream)
{
    const float* x     = (const float*)d_in[0];
    const float* Wq    = (const float*)d_in[1];
    const float* Wk    = (const float*)d_in[2];
    const float* Wv    = (const float*)d_in[3];
    const float* Wx    = (const float*)d_in[4];
    const float* Wy    = (const float*)d_in[5];
    const float* ab    = (const float*)d_in[6];
    const float* Wp    = (const float*)d_in[7];
    const float* bp    = (const float*)d_in[8];
    const float* gamma = (const float*)d_in[9];
    float* out = (float*)d_out;

    unsigned short* posxb = (unsigned short*)d_ws;           // 8*96*32
    unsigned short* posyb  = posxb + 8 * 96 * 32;
    unsigned short* Wb     = posyb + 8 * 96 * 32;            // 640*256
    unsigned short* Wpb    = Wb + (size_t)640 * 256;         // 256*256
    unsigned short* xs_t   = Wpb + (size_t)256 * 256;        // 2*2304*256
    unsigned short* qbuf   = xs_t + (size_t)2 * NPOS * 256;  // 2*8*2304*32
    unsigned short* oattn_t= qbuf + (size_t)2 * NPOS * 256;  // 2*2304*256
    unsigned short* projb  = oattn_t + (size_t)2 * NPOS * 256; // 2*256*2304
    float* unused_vbuf = (float*)(projb + (size_t)2 * NPOS * 256); // kept for layout
    float* unused_ek   = unused_vbuf + (size_t)2 * 256 * NPOS;
    uint4* vhat  = (uint4*)(unused_ek + 16 * NPOS);          // 16*24*576 uint4

    hipLaunchKernelGGL(prep_extract_kernel, dim3(1064), dim3(256), 0, stream,
                       Wx, Wy, Wk, ab, Wq, Wv, Wp, x, posxb, posyb, Wb, Wpb, xs_t);
    hipLaunchKernelGGL(qkvh_kernel, dim3(4, 72), dim3(256), 0, stream,
                       xs_t, Wb, qbuf, vhat);
    hipLaunchKernelGGL(attn_kernel, dim3(576), dim3(256), 0, stream,
                       qbuf, posxb, posyb, vhat, oattn_t);
    hipLaunchKernelGGL(proj_kernel, dim3(2, 72), dim3(256), 0, stream,
                       oattn_t, Wpb, bp, projb);
    hipLaunchKernelGGL(resize_kernel, dim3((2 * 256 * 96 * 96) / (256 * 4)), dim3(256), 0, stream,
                       projb, x, gamma, out);
}

// Round 7
// 148.233 us; speedup vs baseline: 3.1643x; 1.0137x over previous
//
#include <hip/hip_runtime.h>
#include <hip/hip_bf16.h>
#include <math.h>

// Problem constants
#define NB 2
#define CC 256
#define NPOS 2304   // 48*48
#define NDELTA 95

typedef __attribute__((ext_vector_type(8))) short short8;
typedef __attribute__((ext_vector_type(4))) float floatx4;

__device__ inline unsigned short f2bf(float x) {
    unsigned int u = __float_as_uint(x);
    u = (u + 0x7FFFu + ((u >> 16) & 1u)) >> 16;
    return (unsigned short)u;
}
__device__ inline float bf2f(unsigned short h) {
    return __uint_as_float(((unsigned int)h) << 16);
}
__device__ inline unsigned int pk2(float a, float b) {
    return (unsigned int)f2bf(a) | ((unsigned int)f2bf(b) << 16);
}
__device__ inline unsigned int pkmul(unsigned int a, unsigned int b) {
    __hip_bfloat162 x = *(__hip_bfloat162*)&a;
    __hip_bfloat162 y = *(__hip_bfloat162*)&b;
    __hip_bfloat162 r = __hmul2(x, y);
    return *(unsigned int*)&r;
}

// ---------------------------------------------------------------------------
// Kernel 1: fused prep + extract. Grid 1064.
// Change vs R6: pos-path dot loop vectorized to float4 (was 256 fully-
// uncoalesced scalar loads/thread -> 64 float4 loads).
// ---------------------------------------------------------------------------
__global__ __launch_bounds__(256) void prep_extract_kernel(
    const float* __restrict__ Wx, const float* __restrict__ Wy,
    const float* __restrict__ Wk, const float* __restrict__ ab,
    const float* __restrict__ Wq, const float* __restrict__ Wv,
    const float* __restrict__ Wp, const float* __restrict__ x,
    unsigned short* __restrict__ posxb, unsigned short* __restrict__ posyb,
    unsigned short* __restrict__ Wb, unsigned short* __restrict__ Wpb,
    unsigned short* __restrict__ xs_t)
{
    __shared__ __align__(16) unsigned short Lt[64][264];
    int b = blockIdx.x;
    int t = threadIdx.x;
    if (b < NDELTA) {
        float* emb = (float*)&Lt[0][0];
        float delta = (float)(b - 47);
        if (t < 64) {
            float dim_inv = exp2f(-(float)t * 0.15571537944784511f); // log2(1000)/64
            float ang = 2.0f * delta * dim_inv;
            emb[t]      = sinf(ang);
            emb[t + 64] = cosf(ang);
        }
        __syncthreads();
        float4 sx4 = {0.f,0.f,0.f,0.f}, sy4 = {0.f,0.f,0.f,0.f};
        const float4* wxr = (const float4*)(Wx + t * 128);
        const float4* wyr = (const float4*)(Wy + t * 128);
        const float4* e4  = (const float4*)emb;
        for (int f = 0; f < 32; ++f) {
            float4 e = e4[f], a = wxr[f], bb = wyr[f];
            sx4.x += e.x * a.x;  sx4.y += e.y * a.y;
            sx4.z += e.z * a.z;  sx4.w += e.w * a.w;
            sy4.x += e.x * bb.x; sy4.y += e.y * bb.y;
            sy4.z += e.z * bb.z; sy4.w += e.w * bb.w;
        }
        float sx = (sx4.x + sx4.y) + (sx4.z + sx4.w);
        float sy = (sy4.x + sy4.y) + (sy4.z + sy4.w);
        const float inv_sqrt2 = 0.70710678118654752440f;
        int g = t >> 5, d = t & 31;
        posxb[((size_t)g * 96 + b) * 32 + d] = f2bf(sx * inv_sqrt2);
        posyb[((size_t)g * 96 + b) * 32 + d] = f2bf(sy * inv_sqrt2);
    } else if (b == NDELTA) {
        int g = t >> 5, d = t & 31;
        posxb[((size_t)g * 96 + 95) * 32 + d] = 0;
        posyb[((size_t)g * 96 + 95) * 32 + d] = 0;
    } else if (b < 96 + 640) {
        int o = b - 96;
        float v = 0.f;
        if (o < 256)      v = Wq[o * 256 + t];
        else if (o < 512) v = Wv[(o - 256) * 256 + t];
        else if (o < 520) {
            int g = o - 512;
            float s = 0.f;
            for (int d = 0; d < 32; ++d)
                s += ab[g * 32 + d] * Wk[(g * 32 + d) * 256 + t];
            v = s;
        }
        Wb[(size_t)o * 256 + t] = f2bf(v);
    } else if (b < 992) {
        int o = b - 736;
        Wpb[(size_t)o * 256 + t] = f2bf(Wp[o * 256 + t]);
    } else {
        // --- extract: x[:, :, ::2, ::2] -> bf16 transposed ---
        int blk = b - 992;
        int pt = blk % 36;
        int n = blk / 36;
        int p0 = pt * 64;
        int cw = t >> 4;      // 0..15
        int pl = t & 15;

        for (int cc = 0; cc < 16; ++cc) {
            int c = cc * 16 + cw;
            const float* src = x + ((size_t)(n * 256 + c)) * (96 * 96);
            #pragma unroll
            for (int k = 0; k < 4; ++k) {
                int p = p0 + pl + k * 16;
                int i = p / 48, j = p - i * 48;
                Lt[pl + k * 16][c] = f2bf(src[(2 * i) * 96 + 2 * j]);
            }
        }
        __syncthreads();
        #pragma unroll
        for (int it = 0; it < 8; ++it) {
            int s = t + it * 256;
            int p = s >> 5, c8 = s & 31;
            uint4 v = *(const uint4*)&Lt[p][c8 * 8];
            *(uint4*)(xs_t + ((size_t)(n * NPOS + p0 + p)) * 256 + c8 * 8) = v;
        }
    }
}

// ---------------------------------------------------------------------------
// Kernel 2: fused Q projection + V-hat. Grid (4, 72). (verbatim R6, verified)
// ---------------------------------------------------------------------------
__global__ __launch_bounds__(256, 2) void qkvh_kernel(
    const unsigned short* __restrict__ xs_t, const unsigned short* __restrict__ Wb,
    unsigned short* __restrict__ qbuf, uint4* __restrict__ vhat)
{
    __shared__ __align__(16) unsigned short Vt[4][33][72];
    int mT = blockIdx.x;           // 0..3
    int nT = blockIdx.y;           // 0..71
    int t = threadIdx.x;
    int wm = t >> 6, L = t & 63, l16 = L & 15, oct = L >> 4;
    int colBase = nT * 64;
    int n = colBase / NPOS;
    int p0 = colBase - n * NPOS;
    int o_w = mT * 128 + wm * 32;
    bool isV = (mT >= 2);
    int gv = (mT & 1) * 4 + wm;    // head for v-path

    const unsigned short* A0 = Wb + (size_t)(o_w + l16) * 256 + oct * 8;
    const unsigned short* A1 = A0 + 16 * 256;
    const unsigned short* AE = Wb + (size_t)(512 + gv) * 256 + oct * 8;
    const unsigned short* B0 = xs_t + ((size_t)(n * NPOS + p0 + l16)) * 256 + oct * 8;

    floatx4 acc[2][4] = {};
    floatx4 accE[4] = {};
    #pragma unroll
    for (int kc = 0; kc < 8; ++kc) {
        int k0 = kc * 32;
        short8 a0 = *(const short8*)(A0 + k0);
        short8 a1 = *(const short8*)(A1 + k0);
        short8 b0 = *(const short8*)(B0 + k0);
        short8 b1 = *(const short8*)(B0 + 16 * 256 + k0);
        short8 b2 = *(const short8*)(B0 + 32 * 256 + k0);
        short8 b3 = *(const short8*)(B0 + 48 * 256 + k0);
        acc[0][0] = __builtin_amdgcn_mfma_f32_16x16x32_bf16(a0, b0, acc[0][0], 0, 0, 0);
        acc[0][1] = __builtin_amdgcn_mfma_f32_16x16x32_bf16(a0, b1, acc[0][1], 0, 0, 0);
        acc[0][2] = __builtin_amdgcn_mfma_f32_16x16x32_bf16(a0, b2, acc[0][2], 0, 0, 0);
        acc[0][3] = __builtin_amdgcn_mfma_f32_16x16x32_bf16(a0, b3, acc[0][3], 0, 0, 0);
        acc[1][0] = __builtin_amdgcn_mfma_f32_16x16x32_bf16(a1, b0, acc[1][0], 0, 0, 0);
        acc[1][1] = __builtin_amdgcn_mfma_f32_16x16x32_bf16(a1, b1, acc[1][1], 0, 0, 0);
        acc[1][2] = __builtin_amdgcn_mfma_f32_16x16x32_bf16(a1, b2, acc[1][2], 0, 0, 0);
        acc[1][3] = __builtin_amdgcn_mfma_f32_16x16x32_bf16(a1, b3, acc[1][3], 0, 0, 0);
        if (isV) {
            short8 ae = *(const short8*)(AE + k0);
            accE[0] = __builtin_amdgcn_mfma_f32_16x16x32_bf16(ae, b0, accE[0], 0, 0, 0);
            accE[1] = __builtin_amdgcn_mfma_f32_16x16x32_bf16(ae, b1, accE[1], 0, 0, 0);
            accE[2] = __builtin_amdgcn_mfma_f32_16x16x32_bf16(ae, b2, accE[2], 0, 0, 0);
            accE[3] = __builtin_amdgcn_mfma_f32_16x16x32_bf16(ae, b3, accE[3], 0, 0, 0);
        }
    }

    if (!isV) {
        #pragma unroll
        for (int af = 0; af < 2; ++af) {
            int ob = o_w + af * 16 + oct * 4;
            int gq = ob >> 5, d0 = ob & 31;
            #pragma unroll
            for (int f = 0; f < 4; ++f) {
                int p = p0 + f * 16 + l16;
                uint2 w;
                w.x = pk2(acc[af][f][0], acc[af][f][1]);
                w.y = pk2(acc[af][f][2], acc[af][f][3]);
                *(uint2*)&qbuf[((size_t)(n * 8 + gq) * NPOS + p) * 32 + d0] = w;
            }
        }
    } else {
        #pragma unroll
        for (int f = 0; f < 4; ++f) {
            float e = __expf(accE[f][0]);   // all 4 row-copies identical
            #pragma unroll
            for (int af = 0; af < 2; ++af)
                #pragma unroll
                for (int r = 0; r < 4; ++r)
                    Vt[wm][af * 16 + oct * 4 + r][f * 16 + l16] =
                        f2bf(acc[af][f][r] * e);
            if (oct == 0)
                Vt[wm][32][f * 16 + l16] = f2bf(e);
        }
        __syncthreads();

        int i = L >> 3, j = L & 7;
        int K = p0 + 8 * i;                 // global k within image
        int tile = K / 96;
        int rem = K - tile * 96;
        int cc = rem >> 5;
        int lhi = (rem & 31) >> 3;          // (Ls >> 4) slot
        uint4* vout = vhat + ((size_t)(n * 8 + gv) * 24 + tile) * 576;
        #pragma unroll
        for (int mm = 0; mm < 4; ++mm) {
            int d = j + 8 * mm;
            int nn = d >> 4;
            int Ls = lhi * 16 + (d & 15);
            uint4 w = *(const uint4*)&Vt[wm][d][8 * i];
            vout[(cc * 3 + nn) * 64 + Ls] = w;
        }
        {
            uint4 wa = (j == 0) ? *(const uint4*)&Vt[wm][32][8 * i]
                                : make_uint4(0u, 0u, 0u, 0u);
            vout[(cc * 3 + 2) * 64 + lhi * 16 + j] = wa;
            vout[(cc * 3 + 2) * 64 + lhi * 16 + j + 8] = make_uint4(0u, 0u, 0u, 0u);
        }
    }
}

// ---------------------------------------------------------------------------
// Kernel 3: attention. Change vs R6: __launch_bounds__(256,3) — 3 blocks/CU
// puts all 576 blocks in one scheduling round (was 512 + 64 tail).
// ---------------------------------------------------------------------------
#define DO_TILE(BB, TT) do {                                                   \
    int u0_ = (TT) * 2;                                                        \
    unsigned int y0_ = Ys[qp * 50 + u0_];     y0_ |= y0_ << 16;                \
    unsigned int y1_ = Ys[qp * 50 + u0_ + 1]; y1_ |= y1_ << 16;                \
    unsigned int Yc0_ = y0_, Yc1_ = (o < 2) ? y0_ : y1_, Yc2_ = y1_;           \
    union { unsigned int u[4]; short8 s; } av_;                                \
    av_.u[0] = pkmul(Xp[0], Yc0_); av_.u[1] = pkmul(Xp[1], Yc0_);              \
    av_.u[2] = pkmul(Xp[2], Yc0_); av_.u[3] = pkmul(Xp[3], Yc0_);              \
    acc0 = __builtin_amdgcn_mfma_f32_16x16x32_bf16(av_.s, *(const short8*)&BB[0], acc0, 0, 0, 0); \
    acc1 = __builtin_amdgcn_mfma_f32_16x16x32_bf16(av_.s, *(const short8*)&BB[1], acc1, 0, 0, 0); \
    acc2 = __builtin_amdgcn_mfma_f32_16x16x32_bf16(av_.s, *(const short8*)&BB[2], acc2, 0, 0, 0); \
    av_.u[0] = pkmul(Xp[4], Yc1_); av_.u[1] = pkmul(Xp[5], Yc1_);              \
    av_.u[2] = pkmul(Xp[6], Yc1_); av_.u[3] = pkmul(Xp[7], Yc1_);              \
    acc0 = __builtin_amdgcn_mfma_f32_16x16x32_bf16(av_.s, *(const short8*)&BB[3], acc0, 0, 0, 0); \
    acc1 = __builtin_amdgcn_mfma_f32_16x16x32_bf16(av_.s, *(const short8*)&BB[4], acc1, 0, 0, 0); \
    acc2 = __builtin_amdgcn_mfma_f32_16x16x32_bf16(av_.s, *(const short8*)&BB[5], acc2, 0, 0, 0); \
    av_.u[0] = pkmul(Xp[8], Yc2_); av_.u[1] = pkmul(Xp[9], Yc2_);              \
    av_.u[2] = pkmul(Xp[10], Yc2_); av_.u[3] = pkmul(Xp[11], Yc2_);            \
    acc0 = __builtin_amdgcn_mfma_f32_16x16x32_bf16(av_.s, *(const short8*)&BB[6], acc0, 0, 0, 0); \
    acc1 = __builtin_amdgcn_mfma_f32_16x16x32_bf16(av_.s, *(const short8*)&BB[7], acc1, 0, 0, 0); \
    acc2 = __builtin_amdgcn_mfma_f32_16x16x32_bf16(av_.s, *(const short8*)&BB[8], acc2, 0, 0, 0); \
} while (0)

__global__ __launch_bounds__(256, 3) void attn_kernel(
    const unsigned short* __restrict__ qbuf, const unsigned short* __restrict__ posxb,
    const unsigned short* __restrict__ posyb, const uint4* __restrict__ vhat,
    unsigned short* __restrict__ oattn_t)
{
    __shared__ unsigned short Xs[64 * 50];
    __shared__ unsigned short Ys[64 * 50];
    __shared__ float linv_s[64];

    int blk = blockIdx.x;
    int qt = blk % 36;
    int ng = blk / 36;
    int nb = ng >> 3, g = ng & 7;
    int qbase = qt * 64;
    int t = threadIdx.x;
    int m = t >> 6, L = t & 63;
    int l16 = L & 15, oct = L >> 4;

    // ---- prologue: T = Q·pos^T via MFMA, X/Y = exp(T) into LDS ----
    {
        int qtile0 = qbase + m * 16;
        int hq = qtile0 / 48;
        int wq0 = qtile0 - hq * 48;
        short8 aq = *(const short8*)(qbuf +
            ((size_t)ng * NPOS + qtile0 + l16) * 32 + oct * 8);
        const unsigned short* pxg = posxb + (size_t)g * 96 * 32;
        const unsigned short* pyg = posyb + (size_t)g * 96 * 32;
        floatx4 zero = {0.f, 0.f, 0.f, 0.f};
        #pragma unroll
        for (int j = 0; j < 6; ++j) {
            int dl = j * 16 + l16;
            short8 bx = *(const short8*)(pxg + (size_t)dl * 32 + oct * 8);
            short8 by = *(const short8*)(pyg + (size_t)dl * 32 + oct * 8);
            floatx4 tx = __builtin_amdgcn_mfma_f32_16x16x32_bf16(aq, bx, zero, 0, 0, 0);
            floatx4 ty = __builtin_amdgcn_mfma_f32_16x16x32_bf16(aq, by, zero, 0, 0, 0);
            int u = hq + 47 - dl;
            bool uok = (u >= 0) && (u < 48);
            #pragma unroll
            for (int r = 0; r < 4; ++r) {
                int ql = oct * 4 + r;
                int v = wq0 + ql + 47 - dl;
                if (v >= 0 && v < 48)
                    Xs[(m * 16 + ql) * 50 + v] = f2bf(__expf(tx[r]));
                if (uok)
                    Ys[(m * 16 + ql) * 50 + u] = f2bf(__expf(ty[r]));
            }
        }
    }
    __syncthreads();

    int qp = m * 16 + l16;
    int o = oct;
    unsigned int Xp[12];
    #pragma unroll
    for (int c = 0; c < 3; ++c)
        #pragma unroll
        for (int jj = 0; jj < 4; ++jj) {
            int k = c * 32 + o * 8 + jj * 2;
            int v0 = (k < 48) ? k : k - 48;
            Xp[c * 4 + jj] = *(const unsigned int*)&Xs[qp * 50 + v0];
        }

    floatx4 acc0 = {0.f, 0.f, 0.f, 0.f};
    floatx4 acc1 = {0.f, 0.f, 0.f, 0.f};
    floatx4 acc2 = {0.f, 0.f, 0.f, 0.f};

    const uint4* vb = vhat + (size_t)ng * 24 * 576 + L;
    uint4 Abuf[9], Bbuf[9];
    #pragma unroll
    for (int gg = 0; gg < 9; ++gg) Abuf[gg] = vb[gg * 64];

    for (int tile = 0; tile < 24; tile += 2) {
        const uint4* sB = vb + (tile + 1) * 576;
        #pragma unroll
        for (int gg = 0; gg < 9; ++gg) Bbuf[gg] = sB[gg * 64];
        DO_TILE(Abuf, tile);
        if (tile + 2 < 24) {
            const uint4* sA = vb + (tile + 2) * 576;
            #pragma unroll
            for (int gg = 0; gg < 9; ++gg) Abuf[gg] = sA[gg * 64];
        }
        DO_TILE(Bbuf, tile + 1);
    }

    if ((L & 15) == 0) {
        int qc = m * 16 + (L >> 4) * 4;
        #pragma unroll
        for (int r = 0; r < 4; ++r)
            linv_s[qc + r] = 1.0f / acc2[r];
    }
    __syncthreads();
    {
        int qc = m * 16 + (L >> 4) * 4;
        int d0 = L & 15;
        #pragma unroll
        for (int r = 0; r < 4; ++r) {
            float lir = linv_s[qc + r];
            size_t row = ((size_t)nb * NPOS + qbase + qc + r) * 256;
            oattn_t[row + g * 32 + d0]      = f2bf(acc0[r] * lir);
            oattn_t[row + g * 32 + 16 + d0] = f2bf(acc1[r] * lir);
        }
    }
}

// ---------------------------------------------------------------------------
// Kernel 4: output projection — verbatim R2/R6 (grid (2,72), N=64).
// ---------------------------------------------------------------------------
__global__ __launch_bounds__(256, 2) void proj_kernel(
    const unsigned short* __restrict__ oattn_t, const unsigned short* __restrict__ Wpb,
    const float* __restrict__ bpv, unsigned short* __restrict__ projb)
{
    int mT = blockIdx.x;           // 0..1
    int nT = blockIdx.y;           // 0..71
    int t = threadIdx.x;
    int wm = t >> 6, L = t & 63, l16 = L & 15, oct = L >> 4;
    int colBase = nT * 64;
    int n = colBase / NPOS;
    int p0 = colBase - n * NPOS;
    int o_w = mT * 128 + wm * 32;

    const unsigned short* A0 = Wpb + (size_t)(o_w + l16) * 256 + oct * 8;
    const unsigned short* A1 = A0 + 16 * 256;
    const unsigned short* B0 = oattn_t + ((size_t)(n * NPOS + p0 + l16)) * 256 + oct * 8;

    floatx4 acc[2][4] = {};
    #pragma unroll
    for (int kc = 0; kc < 8; ++kc) {
        int k0 = kc * 32;
        short8 a0 = *(const short8*)(A0 + k0);
        short8 a1 = *(const short8*)(A1 + k0);
        short8 b0 = *(const short8*)(B0 + k0);
        short8 b1 = *(const short8*)(B0 + 16 * 256 + k0);
        short8 b2 = *(const short8*)(B0 + 32 * 256 + k0);
        short8 b3 = *(const short8*)(B0 + 48 * 256 + k0);
        acc[0][0] = __builtin_amdgcn_mfma_f32_16x16x32_bf16(a0, b0, acc[0][0], 0, 0, 0);
        acc[0][1] = __builtin_amdgcn_mfma_f32_16x16x32_bf16(a0, b1, acc[0][1], 0, 0, 0);
        acc[0][2] = __builtin_amdgcn_mfma_f32_16x16x32_bf16(a0, b2, acc[0][2], 0, 0, 0);
        acc[0][3] = __builtin_amdgcn_mfma_f32_16x16x32_bf16(a0, b3, acc[0][3], 0, 0, 0);
        acc[1][0] = __builtin_amdgcn_mfma_f32_16x16x32_bf16(a1, b0, acc[1][0], 0, 0, 0);
        acc[1][1] = __builtin_amdgcn_mfma_f32_16x16x32_bf16(a1, b1, acc[1][1], 0, 0, 0);
        acc[1][2] = __builtin_amdgcn_mfma_f32_16x16x32_bf16(a1, b2, acc[1][2], 0, 0, 0);
        acc[1][3] = __builtin_amdgcn_mfma_f32_16x16x32_bf16(a1, b3, acc[1][3], 0, 0, 0);
    }

    #pragma unroll
    for (int af = 0; af < 2; ++af) {
        #pragma unroll
        for (int f = 0; f < 4; ++f) {
            int p = p0 + f * 16 + l16;
            #pragma unroll
            for (int r = 0; r < 4; ++r) {
                int o = o_w + af * 16 + oct * 4 + r;
                projb[((size_t)(n * 256 + o)) * NPOS + p] = f2bf(acc[af][f][r] + bpv[o]);
            }
        }
    }
}

// ---------------------------------------------------------------------------
// Kernel 5: bilinear 48->96 upsample + residual, 4 px/thread.
// Change vs R6: shared column loads — 4 cols x 2 rows loaded once and reused
// across the 4 output pixels (8 bf16 loads/thread, was 16).
// ---------------------------------------------------------------------------
__global__ __launch_bounds__(256) void resize_kernel(
    const unsigned short* __restrict__ projb, const float* __restrict__ x,
    const float* __restrict__ gamma, float* __restrict__ out)
{
    int idx4 = blockIdx.x * 256 + threadIdx.x;   // each handles 4 J
    int J0 = (idx4 % 24) * 4;
    int tmp = idx4 / 24;
    int I = tmp % 96;
    int nc = tmp / 96;

    int jr = I >> 1;
    int r0, r1; float w0, w1;
    if ((I & 1) == 0) { r0 = (jr > 0) ? jr - 1 : 0; r1 = jr; w0 = 0.25f; w1 = 0.75f; }
    else              { r0 = jr; r1 = (jr < 47) ? jr + 1 : 47; w0 = 0.75f; w1 = 0.25f; }

    int jcb = J0 >> 1;                       // 0..22 (even)
    int cm1 = (jcb > 0) ? jcb - 1 : 0;
    int c2  = jcb + 2;                       // <= 24 < 48, no clamp needed

    const unsigned short* P = projb + (size_t)nc * NPOS;
    const unsigned short* Pr0 = P + r0 * 48;
    const unsigned short* Pr1 = P + r1 * 48;
    float a0 = bf2f(Pr0[cm1]),   a1 = bf2f(Pr0[jcb]);
    float a2 = bf2f(Pr0[jcb+1]), a3 = bf2f(Pr0[c2]);
    float b0 = bf2f(Pr1[cm1]),   b1 = bf2f(Pr1[jcb]);
    float b2 = bf2f(Pr1[jcb+1]), b3 = bf2f(Pr1[c2]);

    // horizontal blends per output pixel k (verified vs original clamp logic):
    //  k=0: .25*a0+.75*a1 ;  k=1: .75*a1+.25*a2
    //  k=2: .25*a1+.75*a2 ;  k=3: .75*a2+.25*a3
    float hA[4], hB[4];
    hA[0] = 0.25f * a0 + 0.75f * a1;  hB[0] = 0.25f * b0 + 0.75f * b1;
    hA[1] = 0.75f * a1 + 0.25f * a2;  hB[1] = 0.75f * b1 + 0.25f * b2;
    hA[2] = 0.25f * a1 + 0.75f * a2;  hB[2] = 0.25f * b1 + 0.75f * b2;
    hA[3] = 0.75f * a2 + 0.25f * a3;  hB[3] = 0.75f * b2 + 0.25f * b3;

    size_t base = ((size_t)nc * 96 + I) * 96 + J0;
    float4 xv = *(const float4*)(x + base);
    float gm = gamma[0];
    float4 ov;
    ov.x = gm * (w0 * hA[0] + w1 * hB[0]) + xv.x;
    ov.y = gm * (w0 * hA[1] + w1 * hB[1]) + xv.y;
    ov.z = gm * (w0 * hA[2] + w1 * hB[2]) + xv.z;
    ov.w = gm * (w0 * hA[3] + w1 * hB[3]) + xv.w;
    *(float4*)(out + base) = ov;
}

// ---------------------------------------------------------------------------
extern "C" void kernel_launch(void* const* d_in, const int* in_sizes, int n_in,
                              void* d_out, int out_size, void* d_ws, size_t ws_size,
                              hipStream_t stream)
{
    const float* x     = (const float*)d_in[0];
    const float* Wq    = (const float*)d_in[1];
    const float* Wk    = (const float*)d_in[2];
    const float* Wv    = (const float*)d_in[3];
    const float* Wx    = (const float*)d_in[4];
    const float* Wy    = (const float*)d_in[5];
    const float* ab    = (const float*)d_in[6];
    const float* Wp    = (const float*)d_in[7];
    const float* bp    = (const float*)d_in[8];
    const float* gamma = (const float*)d_in[9];
    float* out = (float*)d_out;

    unsigned short* posxb = (unsigned short*)d_ws;           // 8*96*32
    unsigned short* posyb  = posxb + 8 * 96 * 32;
    unsigned short* Wb     = posyb + 8 * 96 * 32;            // 640*256
    unsigned short* Wpb    = Wb + (size_t)640 * 256;         // 256*256
    unsigned short* xs_t   = Wpb + (size_t)256 * 256;        // 2*2304*256
    unsigned short* qbuf   = xs_t + (size_t)2 * NPOS * 256;  // 2*8*2304*32
    unsigned short* oattn_t= qbuf + (size_t)2 * NPOS * 256;  // 2*2304*256
    unsigned short* projb  = oattn_t + (size_t)2 * NPOS * 256; // 2*256*2304
    float* unused_vbuf = (float*)(projb + (size_t)2 * NPOS * 256); // layout keep
    float* unused_ek   = unused_vbuf + (size_t)2 * 256 * NPOS;
    uint4* vhat  = (uint4*)(unused_ek + 16 * NPOS);          // 16*24*576 uint4

    hipLaunchKernelGGL(prep_extract_kernel, dim3(1064), dim3(256), 0, stream,
                       Wx, Wy, Wk, ab, Wq, Wv, Wp, x, posxb, posyb, Wb, Wpb, xs_t);
    hipLaunchKernelGGL(qkvh_kernel, dim3(4, 72), dim3(256), 0, stream,
                       xs_t, Wb, qbuf, vhat);
    hipLaunchKernelGGL(attn_kernel, dim3(576), dim3(256), 0, stream,
                       qbuf, posxb, posyb, vhat, oattn_t);
    hipLaunchKernelGGL(proj_kernel, dim3(2, 72), dim3(256), 0, stream,
                       oattn_t, Wpb, bp, projb);
    hipLaunchKernelGGL(resize_kernel, dim3((2 * 256 * 96 * 96) / (256 * 4)), dim3(256), 0, stream,
                       projb, x, gamma, out);
}

// Round 8
// 143.778 us; speedup vs baseline: 3.2624x; 1.0310x over previous
//
#include <hip/hip_runtime.h>
#include <hip/hip_bf16.h>
#include <math.h>

// Problem constants
#define NB 2
#define CC 256
#define NPOS 2304   // 48*48
#define NDELTA 95

typedef __attribute__((ext_vector_type(8))) short short8;
typedef __attribute__((ext_vector_type(4))) float floatx4;

__device__ inline unsigned short f2bf(float x) {
    unsigned int u = __float_as_uint(x);
    u = (u + 0x7FFFu + ((u >> 16) & 1u)) >> 16;
    return (unsigned short)u;
}
__device__ inline float bf2f(unsigned short h) {
    return __uint_as_float(((unsigned int)h) << 16);
}
__device__ inline unsigned int pk2(float a, float b) {
    return (unsigned int)f2bf(a) | ((unsigned int)f2bf(b) << 16);
}
__device__ inline unsigned int pkmul(unsigned int a, unsigned int b) {
    __hip_bfloat162 x = *(__hip_bfloat162*)&a;
    __hip_bfloat162 y = *(__hip_bfloat162*)&b;
    __hip_bfloat162 r = __hmul2(x, y);
    return *(unsigned int*)&r;
}
// load 8 consecutive floats, round each to bf16 (same f2bf as before) -> A frag
__device__ inline short8 ldA_f32(const float* __restrict__ p) {
    float4 f0 = *(const float4*)p;
    float4 f1 = *(const float4*)(p + 4);
    union { unsigned int u[4]; short8 s; } r;
    r.u[0] = pk2(f0.x, f0.y);
    r.u[1] = pk2(f0.z, f0.w);
    r.u[2] = pk2(f1.x, f1.y);
    r.u[3] = pk2(f1.z, f1.w);
    return r.s;
}

// ---------------------------------------------------------------------------
// Kernel 1: fully fused front end. Grid 640:
//   b < 288:  qkvh block (mT=b%4, nT=b/4): extract x-slice into LDS, A from
//             fp32 weights on the fly, wkeff per-wave in LDS; emits qbuf/vhat.
//   b < 384:  pos delta task (b-288): posxb/posyb rows (incl. pad row 95).
//   b < 640:  Wpb row o=b-384.
// ---------------------------------------------------------------------------
__global__ __launch_bounds__(256, 2) void front_kernel(
    const float* __restrict__ x,  const float* __restrict__ Wq,
    const float* __restrict__ Wv, const float* __restrict__ Wk,
    const float* __restrict__ ab, const float* __restrict__ Wx,
    const float* __restrict__ Wy, const float* __restrict__ Wp,
    unsigned short* __restrict__ posxb, unsigned short* __restrict__ posyb,
    unsigned short* __restrict__ Wpb,
    unsigned short* __restrict__ qbuf, uint4* __restrict__ vhat)
{
    __shared__ __align__(16) unsigned char LDSraw[64 * 264 * 2]; // 33792 B
    __shared__ __align__(16) unsigned short We[4][256];          // wkeff bf16
    int b = blockIdx.x;
    int t = threadIdx.x;

    if (b < 288) {
        unsigned short (*Lt)[264] = (unsigned short (*)[264])LDSraw;
        int mT = b & 3;
        int nT = b >> 2;               // 0..71
        int wm = t >> 6, L = t & 63, l16 = L & 15, oct = L >> 4;
        int colBase = nT * 64;
        int n = colBase / NPOS;
        int p0 = colBase - n * NPOS;
        int o_w = mT * 128 + wm * 32;
        bool isV = (mT >= 2);
        int gv = (mT & 1) * 4 + wm;    // head for v-path

        // ---- stage: extract x[:, :, ::2, ::2] slice -> Lt[64][264] ----
        {
            int cw = t >> 4;      // 0..15
            int pl = t & 15;
            for (int cc = 0; cc < 16; ++cc) {
                int c = cc * 16 + cw;
                const float* src = x + ((size_t)(n * 256 + c)) * (96 * 96);
                #pragma unroll
                for (int k = 0; k < 4; ++k) {
                    int p = p0 + pl + k * 16;
                    int i = p / 48, j = p - i * 48;
                    Lt[pl + k * 16][c] = f2bf(src[(2 * i) * 96 + 2 * j]);
                }
            }
            // per-wave wkeff row (only meaningful for isV waves; cheap anyway)
            if (isV) {
                #pragma unroll
                for (int ci = 0; ci < 4; ++ci) {
                    int c = L + ci * 64;
                    float s = 0.f;
                    for (int d = 0; d < 32; ++d)
                        s += ab[gv * 32 + d] * Wk[(gv * 32 + d) * 256 + c];
                    We[wm][c] = f2bf(s);
                }
            }
        }
        __syncthreads();

        // ---- MFMA loop: A from fp32 weights (on-the-fly bf16), B from Lt ----
        const float* Arow = isV ? (Wv + (size_t)(o_w - 256 + l16) * 256)
                                : (Wq + (size_t)(o_w + l16) * 256);
        floatx4 acc[2][4] = {};
        floatx4 accE[4] = {};
        #pragma unroll
        for (int kc = 0; kc < 8; ++kc) {
            int k0 = kc * 32;
            int col = oct * 8 + k0;
            short8 a0 = ldA_f32(Arow + col);
            short8 a1 = ldA_f32(Arow + 16 * 256 + col);
            short8 b0 = *(const short8*)&Lt[l16][col];
            short8 b1 = *(const short8*)&Lt[l16 + 16][col];
            short8 b2 = *(const short8*)&Lt[l16 + 32][col];
            short8 b3 = *(const short8*)&Lt[l16 + 48][col];
            acc[0][0] = __builtin_amdgcn_mfma_f32_16x16x32_bf16(a0, b0, acc[0][0], 0, 0, 0);
            acc[0][1] = __builtin_amdgcn_mfma_f32_16x16x32_bf16(a0, b1, acc[0][1], 0, 0, 0);
            acc[0][2] = __builtin_amdgcn_mfma_f32_16x16x32_bf16(a0, b2, acc[0][2], 0, 0, 0);
            acc[0][3] = __builtin_amdgcn_mfma_f32_16x16x32_bf16(a0, b3, acc[0][3], 0, 0, 0);
            acc[1][0] = __builtin_amdgcn_mfma_f32_16x16x32_bf16(a1, b0, acc[1][0], 0, 0, 0);
            acc[1][1] = __builtin_amdgcn_mfma_f32_16x16x32_bf16(a1, b1, acc[1][1], 0, 0, 0);
            acc[1][2] = __builtin_amdgcn_mfma_f32_16x16x32_bf16(a1, b2, acc[1][2], 0, 0, 0);
            acc[1][3] = __builtin_amdgcn_mfma_f32_16x16x32_bf16(a1, b3, acc[1][3], 0, 0, 0);
            if (isV) {
                short8 ae = *(const short8*)&We[wm][col];
                accE[0] = __builtin_amdgcn_mfma_f32_16x16x32_bf16(ae, b0, accE[0], 0, 0, 0);
                accE[1] = __builtin_amdgcn_mfma_f32_16x16x32_bf16(ae, b1, accE[1], 0, 0, 0);
                accE[2] = __builtin_amdgcn_mfma_f32_16x16x32_bf16(ae, b2, accE[2], 0, 0, 0);
                accE[3] = __builtin_amdgcn_mfma_f32_16x16x32_bf16(ae, b3, accE[3], 0, 0, 0);
            }
        }

        if (!isV) {
            // ---- Q epilogue: packed uint2 stores into qbuf ----
            #pragma unroll
            for (int af = 0; af < 2; ++af) {
                int ob = o_w + af * 16 + oct * 4;
                int gq = ob >> 5, d0 = ob & 31;
                #pragma unroll
                for (int f = 0; f < 4; ++f) {
                    int p = p0 + f * 16 + l16;
                    uint2 w;
                    w.x = pk2(acc[af][f][0], acc[af][f][1]);
                    w.y = pk2(acc[af][f][2], acc[af][f][3]);
                    *(uint2*)&qbuf[((size_t)(n * 8 + gq) * NPOS + p) * 32 + d0] = w;
                }
            }
        } else {
            // ---- V-hat epilogue; Vt aliases Lt (dead after MFMA loop) ----
            __syncthreads();   // all waves done reading Lt before overwrite
            unsigned short (*Vt)[33][72] = (unsigned short (*)[33][72])LDSraw;
            #pragma unroll
            for (int f = 0; f < 4; ++f) {
                float e = __expf(accE[f][0]);   // all 4 row-copies identical
                #pragma unroll
                for (int af = 0; af < 2; ++af)
                    #pragma unroll
                    for (int r = 0; r < 4; ++r)
                        Vt[wm][af * 16 + oct * 4 + r][f * 16 + l16] =
                            f2bf(acc[af][f][r] * e);
                if (oct == 0)
                    Vt[wm][32][f * 16 + l16] = f2bf(e);
            }
            __syncthreads();

            int i = L >> 3, j = L & 7;
            int K = p0 + 8 * i;                 // global k within image
            int tile = K / 96;
            int rem = K - tile * 96;
            int cc = rem >> 5;
            int lhi = (rem & 31) >> 3;          // (Ls >> 4) slot
            uint4* vout = vhat + ((size_t)(n * 8 + gv) * 24 + tile) * 576;
            #pragma unroll
            for (int mm = 0; mm < 4; ++mm) {
                int d = j + 8 * mm;
                int nn = d >> 4;
                int Ls = lhi * 16 + (d & 15);
                uint4 w = *(const uint4*)&Vt[wm][d][8 * i];
                vout[(cc * 3 + nn) * 64 + Ls] = w;
            }
            {
                uint4 wa = (j == 0) ? *(const uint4*)&Vt[wm][32][8 * i]
                                    : make_uint4(0u, 0u, 0u, 0u);
                vout[(cc * 3 + 2) * 64 + lhi * 16 + j] = wa;
                vout[(cc * 3 + 2) * 64 + lhi * 16 + j + 8] = make_uint4(0u, 0u, 0u, 0u);
            }
        }
    } else if (b < 384) {
        int task = b - 288;                 // 0..95
        if (task < NDELTA) {
            float* emb = (float*)LDSraw;
            float delta = (float)(task - 47);
            if (t < 64) {
                float dim_inv = exp2f(-(float)t * 0.15571537944784511f); // log2(1000)/64
                float ang = 2.0f * delta * dim_inv;
                emb[t]      = sinf(ang);
                emb[t + 64] = cosf(ang);
            }
            __syncthreads();
            float4 sx4 = {0.f,0.f,0.f,0.f}, sy4 = {0.f,0.f,0.f,0.f};
            const float4* wxr = (const float4*)(Wx + t * 128);
            const float4* wyr = (const float4*)(Wy + t * 128);
            const float4* e4  = (const float4*)emb;
            for (int f = 0; f < 32; ++f) {
                float4 e = e4[f], a = wxr[f], bb = wyr[f];
                sx4.x += e.x * a.x;  sx4.y += e.y * a.y;
                sx4.z += e.z * a.z;  sx4.w += e.w * a.w;
                sy4.x += e.x * bb.x; sy4.y += e.y * bb.y;
                sy4.z += e.z * bb.z; sy4.w += e.w * bb.w;
            }
            float sx = (sx4.x + sx4.y) + (sx4.z + sx4.w);
            float sy = (sy4.x + sy4.y) + (sy4.z + sy4.w);
            const float inv_sqrt2 = 0.70710678118654752440f;
            int g = t >> 5, d = t & 31;
            posxb[((size_t)g * 96 + task) * 32 + d] = f2bf(sx * inv_sqrt2);
            posyb[((size_t)g * 96 + task) * 32 + d] = f2bf(sy * inv_sqrt2);
        } else {
            int g = t >> 5, d = t & 31;
            posxb[((size_t)g * 96 + 95) * 32 + d] = 0;
            posyb[((size_t)g * 96 + 95) * 32 + d] = 0;
        }
    } else {
        int o = b - 384;
        Wpb[(size_t)o * 256 + t] = f2bf(Wp[o * 256 + t]);
    }
}

// ---------------------------------------------------------------------------
// Kernel 2: attention (verbatim R7: r8 structure, __launch_bounds__(256,3)).
// ---------------------------------------------------------------------------
#define DO_TILE(BB, TT) do {                                                   \
    int u0_ = (TT) * 2;                                                        \
    unsigned int y0_ = Ys[qp * 50 + u0_];     y0_ |= y0_ << 16;                \
    unsigned int y1_ = Ys[qp * 50 + u0_ + 1]; y1_ |= y1_ << 16;                \
    unsigned int Yc0_ = y0_, Yc1_ = (o < 2) ? y0_ : y1_, Yc2_ = y1_;           \
    union { unsigned int u[4]; short8 s; } av_;                                \
    av_.u[0] = pkmul(Xp[0], Yc0_); av_.u[1] = pkmul(Xp[1], Yc0_);              \
    av_.u[2] = pkmul(Xp[2], Yc0_); av_.u[3] = pkmul(Xp[3], Yc0_);              \
    acc0 = __builtin_amdgcn_mfma_f32_16x16x32_bf16(av_.s, *(const short8*)&BB[0], acc0, 0, 0, 0); \
    acc1 = __builtin_amdgcn_mfma_f32_16x16x32_bf16(av_.s, *(const short8*)&BB[1], acc1, 0, 0, 0); \
    acc2 = __builtin_amdgcn_mfma_f32_16x16x32_bf16(av_.s, *(const short8*)&BB[2], acc2, 0, 0, 0); \
    av_.u[0] = pkmul(Xp[4], Yc1_); av_.u[1] = pkmul(Xp[5], Yc1_);              \
    av_.u[2] = pkmul(Xp[6], Yc1_); av_.u[3] = pkmul(Xp[7], Yc1_);              \
    acc0 = __builtin_amdgcn_mfma_f32_16x16x32_bf16(av_.s, *(const short8*)&BB[3], acc0, 0, 0, 0); \
    acc1 = __builtin_amdgcn_mfma_f32_16x16x32_bf16(av_.s, *(const short8*)&BB[4], acc1, 0, 0, 0); \
    acc2 = __builtin_amdgcn_mfma_f32_16x16x32_bf16(av_.s, *(const short8*)&BB[5], acc2, 0, 0, 0); \
    av_.u[0] = pkmul(Xp[8], Yc2_); av_.u[1] = pkmul(Xp[9], Yc2_);              \
    av_.u[2] = pkmul(Xp[10], Yc2_); av_.u[3] = pkmul(Xp[11], Yc2_);            \
    acc0 = __builtin_amdgcn_mfma_f32_16x16x32_bf16(av_.s, *(const short8*)&BB[6], acc0, 0, 0, 0); \
    acc1 = __builtin_amdgcn_mfma_f32_16x16x32_bf16(av_.s, *(const short8*)&BB[7], acc1, 0, 0, 0); \
    acc2 = __builtin_amdgcn_mfma_f32_16x16x32_bf16(av_.s, *(const short8*)&BB[8], acc2, 0, 0, 0); \
} while (0)

__global__ __launch_bounds__(256, 3) void attn_kernel(
    const unsigned short* __restrict__ qbuf, const unsigned short* __restrict__ posxb,
    const unsigned short* __restrict__ posyb, const uint4* __restrict__ vhat,
    unsigned short* __restrict__ oattn_t)
{
    __shared__ unsigned short Xs[64 * 50];
    __shared__ unsigned short Ys[64 * 50];
    __shared__ float linv_s[64];

    int blk = blockIdx.x;
    int qt = blk % 36;
    int ng = blk / 36;
    int nb = ng >> 3, g = ng & 7;
    int qbase = qt * 64;
    int t = threadIdx.x;
    int m = t >> 6, L = t & 63;
    int l16 = L & 15, oct = L >> 4;

    // ---- prologue: T = Q·pos^T via MFMA, X/Y = exp(T) into LDS ----
    {
        int qtile0 = qbase + m * 16;
        int hq = qtile0 / 48;
        int wq0 = qtile0 - hq * 48;
        short8 aq = *(const short8*)(qbuf +
            ((size_t)ng * NPOS + qtile0 + l16) * 32 + oct * 8);
        const unsigned short* pxg = posxb + (size_t)g * 96 * 32;
        const unsigned short* pyg = posyb + (size_t)g * 96 * 32;
        floatx4 zero = {0.f, 0.f, 0.f, 0.f};
        #pragma unroll
        for (int j = 0; j < 6; ++j) {
            int dl = j * 16 + l16;
            short8 bx = *(const short8*)(pxg + (size_t)dl * 32 + oct * 8);
            short8 by = *(const short8*)(pyg + (size_t)dl * 32 + oct * 8);
            floatx4 tx = __builtin_amdgcn_mfma_f32_16x16x32_bf16(aq, bx, zero, 0, 0, 0);
            floatx4 ty = __builtin_amdgcn_mfma_f32_16x16x32_bf16(aq, by, zero, 0, 0, 0);
            int u = hq + 47 - dl;
            bool uok = (u >= 0) && (u < 48);
            #pragma unroll
            for (int r = 0; r < 4; ++r) {
                int ql = oct * 4 + r;
                int v = wq0 + ql + 47 - dl;
                if (v >= 0 && v < 48)
                    Xs[(m * 16 + ql) * 50 + v] = f2bf(__expf(tx[r]));
                if (uok)
                    Ys[(m * 16 + ql) * 50 + u] = f2bf(__expf(ty[r]));
            }
        }
    }
    __syncthreads();

    int qp = m * 16 + l16;
    int o = oct;
    unsigned int Xp[12];
    #pragma unroll
    for (int c = 0; c < 3; ++c)
        #pragma unroll
        for (int jj = 0; jj < 4; ++jj) {
            int k = c * 32 + o * 8 + jj * 2;
            int v0 = (k < 48) ? k : k - 48;
            Xp[c * 4 + jj] = *(const unsigned int*)&Xs[qp * 50 + v0];
        }

    floatx4 acc0 = {0.f, 0.f, 0.f, 0.f};
    floatx4 acc1 = {0.f, 0.f, 0.f, 0.f};
    floatx4 acc2 = {0.f, 0.f, 0.f, 0.f};

    const uint4* vb = vhat + (size_t)ng * 24 * 576 + L;
    uint4 Abuf[9], Bbuf[9];
    #pragma unroll
    for (int gg = 0; gg < 9; ++gg) Abuf[gg] = vb[gg * 64];

    for (int tile = 0; tile < 24; tile += 2) {
        const uint4* sB = vb + (tile + 1) * 576;
        #pragma unroll
        for (int gg = 0; gg < 9; ++gg) Bbuf[gg] = sB[gg * 64];
        DO_TILE(Abuf, tile);
        if (tile + 2 < 24) {
            const uint4* sA = vb + (tile + 2) * 576;
            #pragma unroll
            for (int gg = 0; gg < 9; ++gg) Abuf[gg] = sA[gg * 64];
        }
        DO_TILE(Bbuf, tile + 1);
    }

    if ((L & 15) == 0) {
        int qc = m * 16 + (L >> 4) * 4;
        #pragma unroll
        for (int r = 0; r < 4; ++r)
            linv_s[qc + r] = 1.0f / acc2[r];
    }
    __syncthreads();
    {
        int qc = m * 16 + (L >> 4) * 4;
        int d0 = L & 15;
        #pragma unroll
        for (int r = 0; r < 4; ++r) {
            float lir = linv_s[qc + r];
            size_t row = ((size_t)nb * NPOS + qbase + qc + r) * 256;
            oattn_t[row + g * 32 + d0]      = f2bf(acc0[r] * lir);
            oattn_t[row + g * 32 + 16 + d0] = f2bf(acc1[r] * lir);
        }
    }
}

// ---------------------------------------------------------------------------
// Kernel 3: output projection — verbatim (grid (2,72), N=64).
// ---------------------------------------------------------------------------
__global__ __launch_bounds__(256, 2) void proj_kernel(
    const unsigned short* __restrict__ oattn_t, const unsigned short* __restrict__ Wpb,
    const float* __restrict__ bpv, unsigned short* __restrict__ projb)
{
    int mT = blockIdx.x;           // 0..1
    int nT = blockIdx.y;           // 0..71
    int t = threadIdx.x;
    int wm = t >> 6, L = t & 63, l16 = L & 15, oct = L >> 4;
    int colBase = nT * 64;
    int n = colBase / NPOS;
    int p0 = colBase - n * NPOS;
    int o_w = mT * 128 + wm * 32;

    const unsigned short* A0 = Wpb + (size_t)(o_w + l16) * 256 + oct * 8;
    const unsigned short* A1 = A0 + 16 * 256;
    const unsigned short* B0 = oattn_t + ((size_t)(n * NPOS + p0 + l16)) * 256 + oct * 8;

    floatx4 acc[2][4] = {};
    #pragma unroll
    for (int kc = 0; kc < 8; ++kc) {
        int k0 = kc * 32;
        short8 a0 = *(const short8*)(A0 + k0);
        short8 a1 = *(const short8*)(A1 + k0);
        short8 b0 = *(const short8*)(B0 + k0);
        short8 b1 = *(const short8*)(B0 + 16 * 256 + k0);
        short8 b2 = *(const short8*)(B0 + 32 * 256 + k0);
        short8 b3 = *(const short8*)(B0 + 48 * 256 + k0);
        acc[0][0] = __builtin_amdgcn_mfma_f32_16x16x32_bf16(a0, b0, acc[0][0], 0, 0, 0);
        acc[0][1] = __builtin_amdgcn_mfma_f32_16x16x32_bf16(a0, b1, acc[0][1], 0, 0, 0);
        acc[0][2] = __builtin_amdgcn_mfma_f32_16x16x32_bf16(a0, b2, acc[0][2], 0, 0, 0);
        acc[0][3] = __builtin_amdgcn_mfma_f32_16x16x32_bf16(a0, b3, acc[0][3], 0, 0, 0);
        acc[1][0] = __builtin_amdgcn_mfma_f32_16x16x32_bf16(a1, b0, acc[1][0], 0, 0, 0);
        acc[1][1] = __builtin_amdgcn_mfma_f32_16x16x32_bf16(a1, b1, acc[1][1], 0, 0, 0);
        acc[1][2] = __builtin_amdgcn_mfma_f32_16x16x32_bf16(a1, b2, acc[1][2], 0, 0, 0);
        acc[1][3] = __builtin_amdgcn_mfma_f32_16x16x32_bf16(a1, b3, acc[1][3], 0, 0, 0);
    }

    #pragma unroll
    for (int af = 0; af < 2; ++af) {
        #pragma unroll
        for (int f = 0; f < 4; ++f) {
            int p = p0 + f * 16 + l16;
            #pragma unroll
            for (int r = 0; r < 4; ++r) {
                int o = o_w + af * 16 + oct * 4 + r;
                projb[((size_t)(n * 256 + o)) * NPOS + p] = f2bf(acc[af][f][r] + bpv[o]);
            }
        }
    }
}

// ---------------------------------------------------------------------------
// Kernel 4: bilinear 48->96 upsample + residual, 4 px/thread (verbatim R7).
// ---------------------------------------------------------------------------
__global__ __launch_bounds__(256) void resize_kernel(
    const unsigned short* __restrict__ projb, const float* __restrict__ x,
    const float* __restrict__ gamma, float* __restrict__ out)
{
    int idx4 = blockIdx.x * 256 + threadIdx.x;   // each handles 4 J
    int J0 = (idx4 % 24) * 4;
    int tmp = idx4 / 24;
    int I = tmp % 96;
    int nc = tmp / 96;

    int jr = I >> 1;
    int r0, r1; float w0, w1;
    if ((I & 1) == 0) { r0 = (jr > 0) ? jr - 1 : 0; r1 = jr; w0 = 0.25f; w1 = 0.75f; }
    else              { r0 = jr; r1 = (jr < 47) ? jr + 1 : 47; w0 = 0.75f; w1 = 0.25f; }

    int jcb = J0 >> 1;                       // 0..22 (even)
    int cm1 = (jcb > 0) ? jcb - 1 : 0;
    int c2  = jcb + 2;                       // <= 24 < 48, no clamp needed

    const unsigned short* P = projb + (size_t)nc * NPOS;
    const unsigned short* Pr0 = P + r0 * 48;
    const unsigned short* Pr1 = P + r1 * 48;
    float a0 = bf2f(Pr0[cm1]),   a1 = bf2f(Pr0[jcb]);
    float a2 = bf2f(Pr0[jcb+1]), a3 = bf2f(Pr0[c2]);
    float b0 = bf2f(Pr1[cm1]),   b1 = bf2f(Pr1[jcb]);
    float b2 = bf2f(Pr1[jcb+1]), b3 = bf2f(Pr1[c2]);

    float hA[4], hB[4];
    hA[0] = 0.25f * a0 + 0.75f * a1;  hB[0] = 0.25f * b0 + 0.75f * b1;
    hA[1] = 0.75f * a1 + 0.25f * a2;  hB[1] = 0.75f * b1 + 0.25f * b2;
    hA[2] = 0.25f * a1 + 0.75f * a2;  hB[2] = 0.25f * b1 + 0.75f * b2;
    hA[3] = 0.75f * a2 + 0.25f * a3;  hB[3] = 0.75f * b2 + 0.25f * b3;

    size_t base = ((size_t)nc * 96 + I) * 96 + J0;
    float4 xv = *(const float4*)(x + base);
    float gm = gamma[0];
    float4 ov;
    ov.x = gm * (w0 * hA[0] + w1 * hB[0]) + xv.x;
    ov.y = gm * (w0 * hA[1] + w1 * hB[1]) + xv.y;
    ov.z = gm * (w0 * hA[2] + w1 * hB[2]) + xv.z;
    ov.w = gm * (w0 * hA[3] + w1 * hB[3]) + xv.w;
    *(float4*)(out + base) = ov;
}

// ---------------------------------------------------------------------------
extern "C" void kernel_launch(void* const* d_in, const int* in_sizes, int n_in,
                              void* d_out, int out_size, void* d_ws, size_t ws_size,
                              hipStream_t stream)
{
    const float* x     = (const float*)d_in[0];
    const float* Wq    = (const float*)d_in[1];
    const float* Wk    = (const float*)d_in[2];
    const float* Wv    = (const float*)d_in[3];
    const float* Wx    = (const float*)d_in[4];
    const float* Wy    = (const float*)d_in[5];
    const float* ab    = (const float*)d_in[6];
    const float* Wp    = (const float*)d_in[7];
    const float* bp    = (const float*)d_in[8];
    const float* gamma = (const float*)d_in[9];
    float* out = (float*)d_out;

    unsigned short* posxb = (unsigned short*)d_ws;           // 8*96*32
    unsigned short* posyb  = posxb + 8 * 96 * 32;
    unsigned short* Wpb    = posyb + 8 * 96 * 32;            // 256*256
    unsigned short* qbuf   = Wpb + (size_t)256 * 256;        // 2*8*2304*32
    unsigned short* oattn_t= qbuf + (size_t)2 * NPOS * 256;  // 2*2304*256
    unsigned short* projb  = oattn_t + (size_t)2 * NPOS * 256; // 2*256*2304
    uint4* vhat  = (uint4*)(projb + (size_t)2 * NPOS * 256); // 16*24*576 uint4

    hipLaunchKernelGGL(front_kernel, dim3(640), dim3(256), 0, stream,
                       x, Wq, Wv, Wk, ab, Wx, Wy, Wp,
                       posxb, posyb, Wpb, qbuf, vhat);
    hipLaunchKernelGGL(attn_kernel, dim3(576), dim3(256), 0, stream,
                       qbuf, posxb, posyb, vhat, oattn_t);
    hipLaunchKernelGGL(proj_kernel, dim3(2, 72), dim3(256), 0, stream,
                       oattn_t, Wpb, bp, projb);
    hipLaunchKernelGGL(resize_kernel, dim3((2 * 256 * 96 * 96) / (256 * 4)), dim3(256), 0, stream,
                       projb, x, gamma, out);
}

// Round 9
// 142.954 us; speedup vs baseline: 3.2812x; 1.0058x over previous
//
#include <hip/hip_runtime.h>
#include <hip/hip_bf16.h>
#include <math.h>

// Problem constants
#define NB 2
#define CC 256
#define NPOS 2304   // 48*48
#define NDELTA 95

typedef __attribute__((ext_vector_type(8))) short short8;
typedef __attribute__((ext_vector_type(4))) float floatx4;

__device__ inline unsigned short f2bf(float x) {
    unsigned int u = __float_as_uint(x);
    u = (u + 0x7FFFu + ((u >> 16) & 1u)) >> 16;
    return (unsigned short)u;
}
__device__ inline float bf2f(unsigned short h) {
    return __uint_as_float(((unsigned int)h) << 16);
}
__device__ inline unsigned int pk2(float a, float b) {
    return (unsigned int)f2bf(a) | ((unsigned int)f2bf(b) << 16);
}
__device__ inline unsigned int pkmul(unsigned int a, unsigned int b) {
    __hip_bfloat162 x = *(__hip_bfloat162*)&a;
    __hip_bfloat162 y = *(__hip_bfloat162*)&b;
    __hip_bfloat162 r = __hmul2(x, y);
    return *(unsigned int*)&r;
}
// load 8 consecutive floats, round each to bf16 (same f2bf as before) -> A frag
__device__ inline short8 ldA_f32(const float* __restrict__ p) {
    float4 f0 = *(const float4*)p;
    float4 f1 = *(const float4*)(p + 4);
    union { unsigned int u[4]; short8 s; } r;
    r.u[0] = pk2(f0.x, f0.y);
    r.u[1] = pk2(f0.z, f0.w);
    r.u[2] = pk2(f1.x, f1.y);
    r.u[3] = pk2(f1.z, f1.w);
    return r.s;
}

// ---------------------------------------------------------------------------
// Kernel 1: fully fused front end. Grid 640.
// Change vs R8: __launch_bounds__(256,3) -> all 640 blocks co-resident in one
// scheduling round (was 512 + 128-block second round of heavy qkvh blocks).
// LDS 35840 B x 3 = 107.5 KB <= 160 KB.
// ---------------------------------------------------------------------------
__global__ __launch_bounds__(256, 3) void front_kernel(
    const float* __restrict__ x,  const float* __restrict__ Wq,
    const float* __restrict__ Wv, const float* __restrict__ Wk,
    const float* __restrict__ ab, const float* __restrict__ Wx,
    const float* __restrict__ Wy, const float* __restrict__ Wp,
    unsigned short* __restrict__ posxb, unsigned short* __restrict__ posyb,
    unsigned short* __restrict__ Wpb,
    unsigned short* __restrict__ qbuf, uint4* __restrict__ vhat)
{
    __shared__ __align__(16) unsigned char LDSraw[64 * 264 * 2]; // 33792 B
    __shared__ __align__(16) unsigned short We[4][256];          // wkeff bf16
    int b = blockIdx.x;
    int t = threadIdx.x;

    if (b < 288) {
        unsigned short (*Lt)[264] = (unsigned short (*)[264])LDSraw;
        int mT = b & 3;
        int nT = b >> 2;               // 0..71
        int wm = t >> 6, L = t & 63, l16 = L & 15, oct = L >> 4;
        int colBase = nT * 64;
        int n = colBase / NPOS;
        int p0 = colBase - n * NPOS;
        int o_w = mT * 128 + wm * 32;
        bool isV = (mT >= 2);
        int gv = (mT & 1) * 4 + wm;    // head for v-path

        // ---- stage: extract x[:, :, ::2, ::2] slice -> Lt[64][264] ----
        {
            int cw = t >> 4;      // 0..15
            int pl = t & 15;
            for (int cc = 0; cc < 16; ++cc) {
                int c = cc * 16 + cw;
                const float* src = x + ((size_t)(n * 256 + c)) * (96 * 96);
                #pragma unroll
                for (int k = 0; k < 4; ++k) {
                    int p = p0 + pl + k * 16;
                    int i = p / 48, j = p - i * 48;
                    Lt[pl + k * 16][c] = f2bf(src[(2 * i) * 96 + 2 * j]);
                }
            }
            // per-wave wkeff row (only meaningful for isV waves; cheap anyway)
            if (isV) {
                #pragma unroll
                for (int ci = 0; ci < 4; ++ci) {
                    int c = L + ci * 64;
                    float s = 0.f;
                    for (int d = 0; d < 32; ++d)
                        s += ab[gv * 32 + d] * Wk[(gv * 32 + d) * 256 + c];
                    We[wm][c] = f2bf(s);
                }
            }
        }
        __syncthreads();

        // ---- MFMA loop: A from fp32 weights (on-the-fly bf16), B from Lt ----
        const float* Arow = isV ? (Wv + (size_t)(o_w - 256 + l16) * 256)
                                : (Wq + (size_t)(o_w + l16) * 256);
        floatx4 acc[2][4] = {};
        floatx4 accE[4] = {};
        #pragma unroll
        for (int kc = 0; kc < 8; ++kc) {
            int k0 = kc * 32;
            int col = oct * 8 + k0;
            short8 a0 = ldA_f32(Arow + col);
            short8 a1 = ldA_f32(Arow + 16 * 256 + col);
            short8 b0 = *(const short8*)&Lt[l16][col];
            short8 b1 = *(const short8*)&Lt[l16 + 16][col];
            short8 b2 = *(const short8*)&Lt[l16 + 32][col];
            short8 b3 = *(const short8*)&Lt[l16 + 48][col];
            acc[0][0] = __builtin_amdgcn_mfma_f32_16x16x32_bf16(a0, b0, acc[0][0], 0, 0, 0);
            acc[0][1] = __builtin_amdgcn_mfma_f32_16x16x32_bf16(a0, b1, acc[0][1], 0, 0, 0);
            acc[0][2] = __builtin_amdgcn_mfma_f32_16x16x32_bf16(a0, b2, acc[0][2], 0, 0, 0);
            acc[0][3] = __builtin_amdgcn_mfma_f32_16x16x32_bf16(a0, b3, acc[0][3], 0, 0, 0);
            acc[1][0] = __builtin_amdgcn_mfma_f32_16x16x32_bf16(a1, b0, acc[1][0], 0, 0, 0);
            acc[1][1] = __builtin_amdgcn_mfma_f32_16x16x32_bf16(a1, b1, acc[1][1], 0, 0, 0);
            acc[1][2] = __builtin_amdgcn_mfma_f32_16x16x32_bf16(a1, b2, acc[1][2], 0, 0, 0);
            acc[1][3] = __builtin_amdgcn_mfma_f32_16x16x32_bf16(a1, b3, acc[1][3], 0, 0, 0);
            if (isV) {
                short8 ae = *(const short8*)&We[wm][col];
                accE[0] = __builtin_amdgcn_mfma_f32_16x16x32_bf16(ae, b0, accE[0], 0, 0, 0);
                accE[1] = __builtin_amdgcn_mfma_f32_16x16x32_bf16(ae, b1, accE[1], 0, 0, 0);
                accE[2] = __builtin_amdgcn_mfma_f32_16x16x32_bf16(ae, b2, accE[2], 0, 0, 0);
                accE[3] = __builtin_amdgcn_mfma_f32_16x16x32_bf16(ae, b3, accE[3], 0, 0, 0);
            }
        }

        if (!isV) {
            // ---- Q epilogue: packed uint2 stores into qbuf ----
            #pragma unroll
            for (int af = 0; af < 2; ++af) {
                int ob = o_w + af * 16 + oct * 4;
                int gq = ob >> 5, d0 = ob & 31;
                #pragma unroll
                for (int f = 0; f < 4; ++f) {
                    int p = p0 + f * 16 + l16;
                    uint2 w;
                    w.x = pk2(acc[af][f][0], acc[af][f][1]);
                    w.y = pk2(acc[af][f][2], acc[af][f][3]);
                    *(uint2*)&qbuf[((size_t)(n * 8 + gq) * NPOS + p) * 32 + d0] = w;
                }
            }
        } else {
            // ---- V-hat epilogue; Vt aliases Lt (dead after MFMA loop) ----
            __syncthreads();   // all waves done reading Lt before overwrite
            unsigned short (*Vt)[33][72] = (unsigned short (*)[33][72])LDSraw;
            #pragma unroll
            for (int f = 0; f < 4; ++f) {
                float e = __expf(accE[f][0]);   // all 4 row-copies identical
                #pragma unroll
                for (int af = 0; af < 2; ++af)
                    #pragma unroll
                    for (int r = 0; r < 4; ++r)
                        Vt[wm][af * 16 + oct * 4 + r][f * 16 + l16] =
                            f2bf(acc[af][f][r] * e);
                if (oct == 0)
                    Vt[wm][32][f * 16 + l16] = f2bf(e);
            }
            __syncthreads();

            int i = L >> 3, j = L & 7;
            int K = p0 + 8 * i;                 // global k within image
            int tile = K / 96;
            int rem = K - tile * 96;
            int cc = rem >> 5;
            int lhi = (rem & 31) >> 3;          // (Ls >> 4) slot
            uint4* vout = vhat + ((size_t)(n * 8 + gv) * 24 + tile) * 576;
            #pragma unroll
            for (int mm = 0; mm < 4; ++mm) {
                int d = j + 8 * mm;
                int nn = d >> 4;
                int Ls = lhi * 16 + (d & 15);
                uint4 w = *(const uint4*)&Vt[wm][d][8 * i];
                vout[(cc * 3 + nn) * 64 + Ls] = w;
            }
            {
                uint4 wa = (j == 0) ? *(const uint4*)&Vt[wm][32][8 * i]
                                    : make_uint4(0u, 0u, 0u, 0u);
                vout[(cc * 3 + 2) * 64 + lhi * 16 + j] = wa;
                vout[(cc * 3 + 2) * 64 + lhi * 16 + j + 8] = make_uint4(0u, 0u, 0u, 0u);
            }
        }
    } else if (b < 384) {
        int task = b - 288;                 // 0..95
        if (task < NDELTA) {
            float* emb = (float*)LDSraw;
            float delta = (float)(task - 47);
            if (t < 64) {
                float dim_inv = exp2f(-(float)t * 0.15571537944784511f); // log2(1000)/64
                float ang = 2.0f * delta * dim_inv;
                emb[t]      = sinf(ang);
                emb[t + 64] = cosf(ang);
            }
            __syncthreads();
            float4 sx4 = {0.f,0.f,0.f,0.f}, sy4 = {0.f,0.f,0.f,0.f};
            const float4* wxr = (const float4*)(Wx + t * 128);
            const float4* wyr = (const float4*)(Wy + t * 128);
            const float4* e4  = (const float4*)emb;
            for (int f = 0; f < 32; ++f) {
                float4 e = e4[f], a = wxr[f], bb = wyr[f];
                sx4.x += e.x * a.x;  sx4.y += e.y * a.y;
                sx4.z += e.z * a.z;  sx4.w += e.w * a.w;
                sy4.x += e.x * bb.x; sy4.y += e.y * bb.y;
                sy4.z += e.z * bb.z; sy4.w += e.w * bb.w;
            }
            float sx = (sx4.x + sx4.y) + (sx4.z + sx4.w);
            float sy = (sy4.x + sy4.y) + (sy4.z + sy4.w);
            const float inv_sqrt2 = 0.70710678118654752440f;
            int g = t >> 5, d = t & 31;
            posxb[((size_t)g * 96 + task) * 32 + d] = f2bf(sx * inv_sqrt2);
            posyb[((size_t)g * 96 + task) * 32 + d] = f2bf(sy * inv_sqrt2);
        } else {
            int g = t >> 5, d = t & 31;
            posxb[((size_t)g * 96 + 95) * 32 + d] = 0;
            posyb[((size_t)g * 96 + 95) * 32 + d] = 0;
        }
    } else {
        int o = b - 384;
        Wpb[(size_t)o * 256 + t] = f2bf(Wp[o * 256 + t]);
    }
}

// ---------------------------------------------------------------------------
// Kernel 2: attention. Change vs R8: s_setprio(1) around each DO_TILE's
// pkmul+MFMA cluster (T5 — attn's barrier-free main loop is phase-diverse).
// ---------------------------------------------------------------------------
#define DO_TILE(BB, TT) do {                                                   \
    int u0_ = (TT) * 2;                                                        \
    unsigned int y0_ = Ys[qp * 50 + u0_];     y0_ |= y0_ << 16;                \
    unsigned int y1_ = Ys[qp * 50 + u0_ + 1]; y1_ |= y1_ << 16;                \
    unsigned int Yc0_ = y0_, Yc1_ = (o < 2) ? y0_ : y1_, Yc2_ = y1_;           \
    union { unsigned int u[4]; short8 s; } av_;                                \
    __builtin_amdgcn_s_setprio(1);                                             \
    av_.u[0] = pkmul(Xp[0], Yc0_); av_.u[1] = pkmul(Xp[1], Yc0_);              \
    av_.u[2] = pkmul(Xp[2], Yc0_); av_.u[3] = pkmul(Xp[3], Yc0_);              \
    acc0 = __builtin_amdgcn_mfma_f32_16x16x32_bf16(av_.s, *(const short8*)&BB[0], acc0, 0, 0, 0); \
    acc1 = __builtin_amdgcn_mfma_f32_16x16x32_bf16(av_.s, *(const short8*)&BB[1], acc1, 0, 0, 0); \
    acc2 = __builtin_amdgcn_mfma_f32_16x16x32_bf16(av_.s, *(const short8*)&BB[2], acc2, 0, 0, 0); \
    av_.u[0] = pkmul(Xp[4], Yc1_); av_.u[1] = pkmul(Xp[5], Yc1_);              \
    av_.u[2] = pkmul(Xp[6], Yc1_); av_.u[3] = pkmul(Xp[7], Yc1_);              \
    acc0 = __builtin_amdgcn_mfma_f32_16x16x32_bf16(av_.s, *(const short8*)&BB[3], acc0, 0, 0, 0); \
    acc1 = __builtin_amdgcn_mfma_f32_16x16x32_bf16(av_.s, *(const short8*)&BB[4], acc1, 0, 0, 0); \
    acc2 = __builtin_amdgcn_mfma_f32_16x16x32_bf16(av_.s, *(const short8*)&BB[5], acc2, 0, 0, 0); \
    av_.u[0] = pkmul(Xp[8], Yc2_); av_.u[1] = pkmul(Xp[9], Yc2_);              \
    av_.u[2] = pkmul(Xp[10], Yc2_); av_.u[3] = pkmul(Xp[11], Yc2_);            \
    acc0 = __builtin_amdgcn_mfma_f32_16x16x32_bf16(av_.s, *(const short8*)&BB[6], acc0, 0, 0, 0); \
    acc1 = __builtin_amdgcn_mfma_f32_16x16x32_bf16(av_.s, *(const short8*)&BB[7], acc1, 0, 0, 0); \
    acc2 = __builtin_amdgcn_mfma_f32_16x16x32_bf16(av_.s, *(const short8*)&BB[8], acc2, 0, 0, 0); \
    __builtin_amdgcn_s_setprio(0);                                             \
} while (0)

__global__ __launch_bounds__(256, 3) void attn_kernel(
    const unsigned short* __restrict__ qbuf, const unsigned short* __restrict__ posxb,
    const unsigned short* __restrict__ posyb, const uint4* __restrict__ vhat,
    unsigned short* __restrict__ oattn_t)
{
    __shared__ unsigned short Xs[64 * 50];
    __shared__ unsigned short Ys[64 * 50];
    __shared__ float linv_s[64];

    int blk = blockIdx.x;
    int qt = blk % 36;
    int ng = blk / 36;
    int nb = ng >> 3, g = ng & 7;
    int qbase = qt * 64;
    int t = threadIdx.x;
    int m = t >> 6, L = t & 63;
    int l16 = L & 15, oct = L >> 4;

    // ---- prologue: T = Q·pos^T via MFMA, X/Y = exp(T) into LDS ----
    {
        int qtile0 = qbase + m * 16;
        int hq = qtile0 / 48;
        int wq0 = qtile0 - hq * 48;
        short8 aq = *(const short8*)(qbuf +
            ((size_t)ng * NPOS + qtile0 + l16) * 32 + oct * 8);
        const unsigned short* pxg = posxb + (size_t)g * 96 * 32;
        const unsigned short* pyg = posyb + (size_t)g * 96 * 32;
        floatx4 zero = {0.f, 0.f, 0.f, 0.f};
        #pragma unroll
        for (int j = 0; j < 6; ++j) {
            int dl = j * 16 + l16;
            short8 bx = *(const short8*)(pxg + (size_t)dl * 32 + oct * 8);
            short8 by = *(const short8*)(pyg + (size_t)dl * 32 + oct * 8);
            floatx4 tx = __builtin_amdgcn_mfma_f32_16x16x32_bf16(aq, bx, zero, 0, 0, 0);
            floatx4 ty = __builtin_amdgcn_mfma_f32_16x16x32_bf16(aq, by, zero, 0, 0, 0);
            int u = hq + 47 - dl;
            bool uok = (u >= 0) && (u < 48);
            #pragma unroll
            for (int r = 0; r < 4; ++r) {
                int ql = oct * 4 + r;
                int v = wq0 + ql + 47 - dl;
                if (v >= 0 && v < 48)
                    Xs[(m * 16 + ql) * 50 + v] = f2bf(__expf(tx[r]));
                if (uok)
                    Ys[(m * 16 + ql) * 50 + u] = f2bf(__expf(ty[r]));
            }
        }
    }
    __syncthreads();

    int qp = m * 16 + l16;
    int o = oct;
    unsigned int Xp[12];
    #pragma unroll
    for (int c = 0; c < 3; ++c)
        #pragma unroll
        for (int jj = 0; jj < 4; ++jj) {
            int k = c * 32 + o * 8 + jj * 2;
            int v0 = (k < 48) ? k : k - 48;
            Xp[c * 4 + jj] = *(const unsigned int*)&Xs[qp * 50 + v0];
        }

    floatx4 acc0 = {0.f, 0.f, 0.f, 0.f};
    floatx4 acc1 = {0.f, 0.f, 0.f, 0.f};
    floatx4 acc2 = {0.f, 0.f, 0.f, 0.f};

    const uint4* vb = vhat + (size_t)ng * 24 * 576 + L;
    uint4 Abuf[9], Bbuf[9];
    #pragma unroll
    for (int gg = 0; gg < 9; ++gg) Abuf[gg] = vb[gg * 64];

    for (int tile = 0; tile < 24; tile += 2) {
        const uint4* sB = vb + (tile + 1) * 576;
        #pragma unroll
        for (int gg = 0; gg < 9; ++gg) Bbuf[gg] = sB[gg * 64];
        DO_TILE(Abuf, tile);
        if (tile + 2 < 24) {
            const uint4* sA = vb + (tile + 2) * 576;
            #pragma unroll
            for (int gg = 0; gg < 9; ++gg) Abuf[gg] = sA[gg * 64];
        }
        DO_TILE(Bbuf, tile + 1);
    }

    if ((L & 15) == 0) {
        int qc = m * 16 + (L >> 4) * 4;
        #pragma unroll
        for (int r = 0; r < 4; ++r)
            linv_s[qc + r] = 1.0f / acc2[r];
    }
    __syncthreads();
    {
        int qc = m * 16 + (L >> 4) * 4;
        int d0 = L & 15;
        #pragma unroll
        for (int r = 0; r < 4; ++r) {
            float lir = linv_s[qc + r];
            size_t row = ((size_t)nb * NPOS + qbase + qc + r) * 256;
            oattn_t[row + g * 32 + d0]      = f2bf(acc0[r] * lir);
            oattn_t[row + g * 32 + 16 + d0] = f2bf(acc1[r] * lir);
        }
    }
}

// ---------------------------------------------------------------------------
// Kernel 3: output projection — verbatim (grid (2,72), N=64).
// ---------------------------------------------------------------------------
__global__ __launch_bounds__(256, 2) void proj_kernel(
    const unsigned short* __restrict__ oattn_t, const unsigned short* __restrict__ Wpb,
    const float* __restrict__ bpv, unsigned short* __restrict__ projb)
{
    int mT = blockIdx.x;           // 0..1
    int nT = blockIdx.y;           // 0..71
    int t = threadIdx.x;
    int wm = t >> 6, L = t & 63, l16 = L & 15, oct = L >> 4;
    int colBase = nT * 64;
    int n = colBase / NPOS;
    int p0 = colBase - n * NPOS;
    int o_w = mT * 128 + wm * 32;

    const unsigned short* A0 = Wpb + (size_t)(o_w + l16) * 256 + oct * 8;
    const unsigned short* A1 = A0 + 16 * 256;
    const unsigned short* B0 = oattn_t + ((size_t)(n * NPOS + p0 + l16)) * 256 + oct * 8;

    floatx4 acc[2][4] = {};
    #pragma unroll
    for (int kc = 0; kc < 8; ++kc) {
        int k0 = kc * 32;
        short8 a0 = *(const short8*)(A0 + k0);
        short8 a1 = *(const short8*)(A1 + k0);
        short8 b0 = *(const short8*)(B0 + k0);
        short8 b1 = *(const short8*)(B0 + 16 * 256 + k0);
        short8 b2 = *(const short8*)(B0 + 32 * 256 + k0);
        short8 b3 = *(const short8*)(B0 + 48 * 256 + k0);
        acc[0][0] = __builtin_amdgcn_mfma_f32_16x16x32_bf16(a0, b0, acc[0][0], 0, 0, 0);
        acc[0][1] = __builtin_amdgcn_mfma_f32_16x16x32_bf16(a0, b1, acc[0][1], 0, 0, 0);
        acc[0][2] = __builtin_amdgcn_mfma_f32_16x16x32_bf16(a0, b2, acc[0][2], 0, 0, 0);
        acc[0][3] = __builtin_amdgcn_mfma_f32_16x16x32_bf16(a0, b3, acc[0][3], 0, 0, 0);
        acc[1][0] = __builtin_amdgcn_mfma_f32_16x16x32_bf16(a1, b0, acc[1][0], 0, 0, 0);
        acc[1][1] = __builtin_amdgcn_mfma_f32_16x16x32_bf16(a1, b1, acc[1][1], 0, 0, 0);
        acc[1][2] = __builtin_amdgcn_mfma_f32_16x16x32_bf16(a1, b2, acc[1][2], 0, 0, 0);
        acc[1][3] = __builtin_amdgcn_mfma_f32_16x16x32_bf16(a1, b3, acc[1][3], 0, 0, 0);
    }

    #pragma unroll
    for (int af = 0; af < 2; ++af) {
        #pragma unroll
        for (int f = 0; f < 4; ++f) {
            int p = p0 + f * 16 + l16;
            #pragma unroll
            for (int r = 0; r < 4; ++r) {
                int o = o_w + af * 16 + oct * 4 + r;
                projb[((size_t)(n * 256 + o)) * NPOS + p] = f2bf(acc[af][f][r] + bpv[o]);
            }
        }
    }
}

// ---------------------------------------------------------------------------
// Kernel 4: bilinear 48->96 upsample + residual, 4 px/thread (verbatim).
// ---------------------------------------------------------------------------
__global__ __launch_bounds__(256) void resize_kernel(
    const unsigned short* __restrict__ projb, const float* __restrict__ x,
    const float* __restrict__ gamma, float* __restrict__ out)
{
    int idx4 = blockIdx.x * 256 + threadIdx.x;   // each handles 4 J
    int J0 = (idx4 % 24) * 4;
    int tmp = idx4 / 24;
    int I = tmp % 96;
    int nc = tmp / 96;

    int jr = I >> 1;
    int r0, r1; float w0, w1;
    if ((I & 1) == 0) { r0 = (jr > 0) ? jr - 1 : 0; r1 = jr; w0 = 0.25f; w1 = 0.75f; }
    else              { r0 = jr; r1 = (jr < 47) ? jr + 1 : 47; w0 = 0.75f; w1 = 0.25f; }

    int jcb = J0 >> 1;                       // 0..22 (even)
    int cm1 = (jcb > 0) ? jcb - 1 : 0;
    int c2  = jcb + 2;                       // <= 24 < 48, no clamp needed

    const unsigned short* P = projb + (size_t)nc * NPOS;
    const unsigned short* Pr0 = P + r0 * 48;
    const unsigned short* Pr1 = P + r1 * 48;
    float a0 = bf2f(Pr0[cm1]),   a1 = bf2f(Pr0[jcb]);
    float a2 = bf2f(Pr0[jcb+1]), a3 = bf2f(Pr0[c2]);
    float b0 = bf2f(Pr1[cm1]),   b1 = bf2f(Pr1[jcb]);
    float b2 = bf2f(Pr1[jcb+1]), b3 = bf2f(Pr1[c2]);

    float hA[4], hB[4];
    hA[0] = 0.25f * a0 + 0.75f * a1;  hB[0] = 0.25f * b0 + 0.75f * b1;
    hA[1] = 0.75f * a1 + 0.25f * a2;  hB[1] = 0.75f * b1 + 0.25f * b2;
    hA[2] = 0.25f * a1 + 0.75f * a2;  hB[2] = 0.25f * b1 + 0.75f * b2;
    hA[3] = 0.75f * a2 + 0.25f * a3;  hB[3] = 0.75f * b2 + 0.25f * b3;

    size_t base = ((size_t)nc * 96 + I) * 96 + J0;
    float4 xv = *(const float4*)(x + base);
    float gm = gamma[0];
    float4 ov;
    ov.x = gm * (w0 * hA[0] + w1 * hB[0]) + xv.x;
    ov.y = gm * (w0 * hA[1] + w1 * hB[1]) + xv.y;
    ov.z = gm * (w0 * hA[2] + w1 * hB[2]) + xv.z;
    ov.w = gm * (w0 * hA[3] + w1 * hB[3]) + xv.w;
    *(float4*)(out + base) = ov;
}

// ---------------------------------------------------------------------------
extern "C" void kernel_launch(void* const* d_in, const int* in_sizes, int n_in,
                              void* d_out, int out_size, void* d_ws, size_t ws_size,
                              hipStream_t stream)
{
    const float* x     = (const float*)d_in[0];
    const float* Wq    = (const float*)d_in[1];
    const float* Wk    = (const float*)d_in[2];
    const float* Wv    = (const float*)d_in[3];
    const float* Wx    = (const float*)d_in[4];
    const float* Wy    = (const float*)d_in[5];
    const float* ab    = (const float*)d_in[6];
    const float* Wp    = (const float*)d_in[7];
    const float* bp    = (const float*)d_in[8];
    const float* gamma = (const float*)d_in[9];
    float* out = (float*)d_out;

    unsigned short* posxb = (unsigned short*)d_ws;           // 8*96*32
    unsigned short* posyb  = posxb + 8 * 96 * 32;
    unsigned short* Wpb    = posyb + 8 * 96 * 32;            // 256*256
    unsigned short* qbuf   = Wpb + (size_t)256 * 256;        // 2*8*2304*32
    unsigned short* oattn_t= qbuf + (size_t)2 * NPOS * 256;  // 2*2304*256
    unsigned short* projb  = oattn_t + (size_t)2 * NPOS * 256; // 2*256*2304
    uint4* vhat  = (uint4*)(projb + (size_t)2 * NPOS * 256); // 16*24*576 uint4

    hipLaunchKernelGGL(front_kernel, dim3(640), dim3(256), 0, stream,
                       x, Wq, Wv, Wk, ab, Wx, Wy, Wp,
                       posxb, posyb, Wpb, qbuf, vhat);
    hipLaunchKernelGGL(attn_kernel, dim3(576), dim3(256), 0, stream,
                       qbuf, posxb, posyb, vhat, oattn_t);
    hipLaunchKernelGGL(proj_kernel, dim3(2, 72), dim3(256), 0, stream,
                       oattn_t, Wpb, bp, projb);
    hipLaunchKernelGGL(resize_kernel, dim3((2 * 256 * 96 * 96) / (256 * 4)), dim3(256), 0, stream,
                       projb, x, gamma, out);
}